// Round 18
// baseline (1030.486 us; speedup 1.0000x reference)
//
#include <hip/hip_runtime.h>
#include <cmath>

#define E_TOTAL 524288
#define NB 8

using f32x4 = __attribute__((ext_vector_type(4))) float;
using s16x8 = __attribute__((ext_vector_type(8))) short;
using s16x4 = __attribute__((ext_vector_type(4))) short;

static inline int cdiv(int a, int b) { return (a + b - 1) / b; }

__device__ inline unsigned short bf16_rn(float x) {
  unsigned u = __float_as_uint(x);
  return (unsigned short)((u + 0x7FFFu + ((u >> 16) & 1u)) >> 16);
}
// 3-chunk split: x ~= h + m + l with residual ~2^-24 |x|
__device__ inline void split3(float x, short& h, short& m, short& l) {
  unsigned short hb = bf16_rn(x);
  h = (short)hb;
  float hf = __uint_as_float(((unsigned)hb) << 16);
  float r1 = x - hf;
  unsigned short mb = bf16_rn(r1);
  m = (short)mb;
  float mf = __uint_as_float(((unsigned)mb) << 16);
  l = (short)bf16_rn(r1 - mf);
}

// async global->LDS 16B copy. LDS dest must be WAVE-UNIFORM; HW adds lane*16.
__device__ inline void async_copy16(const short* g, short* l) {
  __builtin_amdgcn_global_load_lds(
      (const __attribute__((address_space(1))) void*)(unsigned long long)(g),
      (__attribute__((address_space(3))) void*)(unsigned)(unsigned long long)(l),
      16, 0, 0);
}

// ---------------- fills ----------------
__global__ void fill_i32(int* p, int v, int n) {
  int i = blockIdx.x * 256 + threadIdx.x;
  if (i < n) p[i] = v;
}

// ---------------- weight split + transpose: W[K][N] fp32 -> WT[N][K] 3x bf16 ----------------
__global__ void split_w_t(const float* __restrict__ W, short* __restrict__ TH,
                          short* __restrict__ TM, short* __restrict__ TL, int K, int N) {
  int i = blockIdx.x * 256 + threadIdx.x;
  if (i >= K * N) return;
  int k = i / N, n = i % N;
  short h, m, l;
  split3(W[i], h, m, l);
  TH[(size_t)n * K + k] = h;
  TM[(size_t)n * K + k] = m;
  TL[(size_t)n * K + k] = l;
}

// ---------------- 3-chunk split-bf16 MFMA GEMM, dbuf + counted vmcnt (T4) ----------------
// stage(next) issues 9 global_load_lds/wave; s_waitcnt vmcnt(9) waits only the
// PREVIOUS tile's 9 (oldest), so new loads fly under the MFMA chain. Raw
// s_barrier (no implicit drain). Two barriers/iter: ready + reads-done.
#define GBM 128
#define GBN 256
#define GBK 32
#define BUFS 36864
#define BOFF 12288

__global__ __launch_bounds__(512) void gemm_mfma(
    const short* __restrict__ AH, const short* __restrict__ AM, const short* __restrict__ AL,
    const short* __restrict__ BH, const short* __restrict__ BM, const short* __restrict__ BL,
    const float* __restrict__ bias, float* __restrict__ C,
    int M, int K, int N, int nblocks) {
  __shared__ __align__(16) short lds[2][BUFS];
  int nwg = gridDim.x;
  int orig = blockIdx.x;
  int q = nwg >> 3, r = nwg & 7;
  int xc = orig & 7, j8 = orig >> 3;
  int wg = (xc < r ? xc * (q + 1) : r * (q + 1) + (xc - r) * q) + j8;
  int bm = (wg / nblocks) * GBM;
  int bn = (wg % nblocks) * GBN;
  int tid = threadIdx.x;
  int wave = tid >> 6, lane = tid & 63;
  int wr = wave >> 2, wc = wave & 3;
  int l15 = lane & 15, l4 = lane >> 4;
  int pa = wave * 64 + lane;
  int ra = pa >> 2, ca = (pa & 3) ^ ((ra >> 1) & 3);
  int gar = bm + ra; gar = gar < M ? gar : 0;
  size_t gaoff = (size_t)gar * K + ca * 8;
  int adest = wave * 512;
  int pb0 = wave * 128 + lane, pb1 = pb0 + 64;
  int rb0 = pb0 >> 2, cb0 = (pb0 & 3) ^ ((rb0 >> 1) & 3);
  int rb1 = pb1 >> 2, cb1 = (pb1 & 3) ^ ((rb1 >> 1) & 3);
  int gbr0 = bn + rb0; gbr0 = gbr0 < N ? gbr0 : 0;
  int gbr1 = bn + rb1; gbr1 = gbr1 < N ? gbr1 : 0;
  size_t gboff0 = (size_t)gbr0 * K + cb0 * 8;
  size_t gboff1 = (size_t)gbr1 * K + cb1 * 8;
  int bdest = BOFF + wave * 1024;

  auto stage = [&](int b, int k0) {
    short* base = lds[b];
    async_copy16(AH + gaoff + k0, base + adest);
    async_copy16(AM + gaoff + k0, base + 4096 + adest);
    async_copy16(AL + gaoff + k0, base + 8192 + adest);
    async_copy16(BH + gboff0 + k0, base + bdest);
    async_copy16(BH + gboff1 + k0, base + bdest + 512);
    async_copy16(BM + gboff0 + k0, base + 8192 + bdest);
    async_copy16(BM + gboff1 + k0, base + 8192 + bdest + 512);
    async_copy16(BL + gboff0 + k0, base + 16384 + bdest);
    async_copy16(BL + gboff1 + k0, base + 16384 + bdest + 512);
  };

  f32x4 acc[4][4] = {};
  int cur = 0;
  stage(0, 0);
  asm volatile("s_waitcnt vmcnt(0)" ::: "memory");
  __builtin_amdgcn_s_barrier();
  for (int k0 = 0; k0 < K; k0 += GBK) {
    if (k0 + GBK < K) {
      stage(cur ^ 1, k0 + GBK);                       // 9 new loads in flight
      asm volatile("s_waitcnt vmcnt(9)" ::: "memory"); // wait prev tile only
    } else {
      asm volatile("s_waitcnt vmcnt(0)" ::: "memory"); // last tile: full wait
    }
    __builtin_amdgcn_s_barrier();   // buf[cur] ready on all waves
    __builtin_amdgcn_sched_barrier(0);
    const short* base = lds[cur];
    s16x8 fah[4], fam[4], fal[4], fbh[4], fbm[4], fbl[4];
#pragma unroll
    for (int mi = 0; mi < 4; ++mi) {
      int row = wr * 64 + mi * 16 + l15;
      int ad = row * 32 + ((l4 ^ ((row >> 1) & 3)) << 3);
      fah[mi] = *(const s16x8*)(base + ad);
      fam[mi] = *(const s16x8*)(base + 4096 + ad);
      fal[mi] = *(const s16x8*)(base + 8192 + ad);
    }
#pragma unroll
    for (int ni = 0; ni < 4; ++ni) {
      int row = wc * 64 + ni * 16 + l15;
      int bd = BOFF + row * 32 + ((l4 ^ ((row >> 1) & 3)) << 3);
      fbh[ni] = *(const s16x8*)(base + bd);
      fbm[ni] = *(const s16x8*)(base + 8192 + bd);
      fbl[ni] = *(const s16x8*)(base + 16384 + bd);
    }
#pragma unroll
    for (int mi = 0; mi < 4; ++mi)
#pragma unroll
      for (int ni = 0; ni < 4; ++ni) {
        acc[mi][ni] = __builtin_amdgcn_mfma_f32_16x16x32_bf16(fah[mi], fbh[ni], acc[mi][ni], 0, 0, 0);
        acc[mi][ni] = __builtin_amdgcn_mfma_f32_16x16x32_bf16(fah[mi], fbm[ni], acc[mi][ni], 0, 0, 0);
        acc[mi][ni] = __builtin_amdgcn_mfma_f32_16x16x32_bf16(fam[mi], fbh[ni], acc[mi][ni], 0, 0, 0);
        acc[mi][ni] = __builtin_amdgcn_mfma_f32_16x16x32_bf16(fah[mi], fbl[ni], acc[mi][ni], 0, 0, 0);
        acc[mi][ni] = __builtin_amdgcn_mfma_f32_16x16x32_bf16(fal[mi], fbh[ni], acc[mi][ni], 0, 0, 0);
        acc[mi][ni] = __builtin_amdgcn_mfma_f32_16x16x32_bf16(fam[mi], fbm[ni], acc[mi][ni], 0, 0, 0);
      }
    __builtin_amdgcn_s_barrier();   // all waves done reading buf[cur]
    cur ^= 1;
  }
#pragma unroll
  for (int ni = 0; ni < 4; ++ni) {
    int col = bn + wc * 64 + ni * 16 + l15;
    if (col >= N) continue;
    float bv = bias ? bias[col] : 0.f;
#pragma unroll
    for (int mi = 0; mi < 4; ++mi) {
      int row0 = bm + wr * 64 + mi * 16 + l4 * 4;
#pragma unroll
      for (int rr = 0; rr < 4; ++rr) {
        int row = row0 + rr;
        if (row < M) C[(size_t)row * N + col] = acc[mi][ni][rr] + bv;
      }
    }
  }
}

// ---------------- CSR build ----------------
__global__ void count_kernel(const int* __restrict__ dst, int* __restrict__ cnt, int E) {
  int e = blockIdx.x * 256 + threadIdx.x;
  if (e >= E) return;
  atomicAdd(&cnt[dst[e]], 1);
}

// scan + fused dis computation
__global__ __launch_bounds__(1024) void scan_kernel(const int* __restrict__ cnt,
                                                    int* __restrict__ offs,
                                                    float* __restrict__ dis, int n) {
  __shared__ int tsum[1024];
  int tid = threadIdx.x;
  int chunk = (n + 1023) / 1024;
  int base = tid * chunk;
  int lsum = 0;
  for (int i = 0; i < chunk; ++i) {
    int idx = base + i;
    if (idx < n) lsum += cnt[idx];
  }
  tsum[tid] = lsum;
  __syncthreads();
  for (int off = 1; off < 1024; off <<= 1) {
    int add = (tid >= off) ? tsum[tid - off] : 0;
    __syncthreads();
    tsum[tid] += add;
    __syncthreads();
  }
  int run = (tid == 0) ? 0 : tsum[tid - 1];
  for (int i = 0; i < chunk; ++i) {
    int idx = base + i;
    if (idx < n) {
      offs[idx] = run;
      int c = cnt[idx];
      run += c;
      dis[idx] = (c > 0) ? (float)(1.0 / sqrt((double)c)) : 0.f;
    }
  }
  if (tid == 1023) offs[n] = run;
}

__global__ void scatter_kernel(const int* __restrict__ src, const int* __restrict__ dst,
                               const int* __restrict__ offs, int* __restrict__ tmpc,
                               int* __restrict__ esrc, int E) {
  int e = blockIdx.x * 256 + threadIdx.x;
  if (e >= E) return;
  int d = dst[e];
  if (d < 0) return;
  int pos = offs[d] + atomicAdd(&tmpc[d], 1);
  esrc[pos] = src[e];
}

// canonicalize bucket order (determinism)
__global__ void sort_buckets(const int* __restrict__ offs, int* __restrict__ esrc, int n) {
  int node = blockIdx.x * 256 + threadIdx.x;
  if (node >= n) return;
  int s0 = offs[node], s1 = offs[node + 1];
  for (int i = s0 + 1; i < s1; ++i) {
    int v = esrc[i];
    int j = i - 1;
    while (j >= s0 && esrc[j] > v) { esrc[j + 1] = esrc[j]; --j; }
    esrc[j + 1] = v;
  }
}

// ---------------- aggregation (wave per node, f32x4, 4-way edge unroll) ----------------
__global__ __launch_bounds__(256) void agg_kernel(
    const float* __restrict__ h, const int* __restrict__ offs,
    const int* __restrict__ esrc, const float* __restrict__ dis,
    const float* __restrict__ bias, float* __restrict__ outf,
    short* __restrict__ outh, short* __restrict__ outm, short* __restrict__ outl,
    int F, int n) {
  int node = blockIdx.x * 4 + (threadIdx.x >> 6);
  if (node >= n) return;
  int lane = threadIdx.x & 63;
  int nf4 = F >> 2;
  int i0 = lane, i1 = lane + 64;
  bool a0 = i0 < nf4, a1 = i1 < nf4;
  f32x4 acc0 = {}, acc1 = {};
  int e0 = offs[node], e1 = offs[node + 1];
  int e = e0;
  for (; e + 4 <= e1; e += 4) {
    int s0 = esrc[e], s1 = esrc[e + 1], s2 = esrc[e + 2], s3 = esrc[e + 3];
    float w0 = dis[s0], w1 = dis[s1], w2 = dis[s2], w3 = dis[s3];
    const f32x4* p0 = (const f32x4*)(h + (size_t)s0 * F);
    const f32x4* p1 = (const f32x4*)(h + (size_t)s1 * F);
    const f32x4* p2 = (const f32x4*)(h + (size_t)s2 * F);
    const f32x4* p3 = (const f32x4*)(h + (size_t)s3 * F);
    if (a0) {
      f32x4 v0 = p0[i0], v1 = p1[i0], v2 = p2[i0], v3 = p3[i0];
      acc0 += v0 * w0;
      acc0 += v1 * w1;
      acc0 += v2 * w2;
      acc0 += v3 * w3;
    }
    if (a1) {
      f32x4 v0 = p0[i1], v1 = p1[i1], v2 = p2[i1], v3 = p3[i1];
      acc1 += v0 * w0;
      acc1 += v1 * w1;
      acc1 += v2 * w2;
      acc1 += v3 * w3;
    }
  }
  for (; e < e1; ++e) {
    int s = esrc[e];
    float w = dis[s];
    const f32x4* hp = (const f32x4*)(h + (size_t)s * F);
    if (a0) acc0 += hp[i0] * w;
    if (a1) acc1 += hp[i1] * w;
  }
  float wd = dis[node];
  acc0 *= wd;
  acc1 *= wd;
  if (outf) {
    const f32x4* b4 = (const f32x4*)bias;
    f32x4* op = (f32x4*)(outf + (size_t)node * F);
    if (a0) op[i0] = acc0 + b4[i0];
    if (a1) op[i1] = acc1 + b4[i1];
  } else {
    short hh[4], mm[4], ll[4];
    if (a0) {
#pragma unroll
      for (int c = 0; c < 4; ++c) split3(acc0[c], hh[c], mm[c], ll[c]);
      *(s16x4*)&outh[(size_t)node * F + i0 * 4] = *(s16x4*)hh;
      *(s16x4*)&outm[(size_t)node * F + i0 * 4] = *(s16x4*)mm;
      *(s16x4*)&outl[(size_t)node * F + i0 * 4] = *(s16x4*)ll;
    }
    if (a1) {
#pragma unroll
      for (int c = 0; c < 4; ++c) split3(acc1[c], hh[c], mm[c], ll[c]);
      *(s16x4*)&outh[(size_t)node * F + i1 * 4] = *(s16x4*)hh;
      *(s16x4*)&outm[(size_t)node * F + i1 * 4] = *(s16x4*)mm;
      *(s16x4*)&outl[(size_t)node * F + i1 * 4] = *(s16x4*)ll;
    }
  }
}

// ---------------- batch norm (two-stage fp64, atomic-free, deterministic) ----------------
#define BNY 512
__global__ void bn_stats_part(const float* __restrict__ x, double* __restrict__ psum,
                              double* __restrict__ psq, int n, int F) {
  int col = blockIdx.x * 256 + threadIdx.x;
  if (col >= F) return;
  double s = 0., q = 0.;
  for (int r = blockIdx.y; r < n; r += gridDim.y) {
    double v = (double)x[(size_t)r * F + col];
    s += v;
    q += v * v;
  }
  psum[blockIdx.y * F + col] = s;
  psq[blockIdx.y * F + col] = q;
}

// one block per column, 64-thread tree reduce (fixed order => deterministic)
__global__ __launch_bounds__(64) void bn_reduce(
    const double* __restrict__ psum, const double* __restrict__ psq,
    const float* __restrict__ g, const float* __restrict__ be,
    float* __restrict__ scf, float* __restrict__ shf,
    double* __restrict__ scd, double* __restrict__ shd, int n, int F) {
  int c = blockIdx.x;
  int lane = threadIdx.x;
  double s = 0., q = 0.;
  for (int p = lane; p < BNY; p += 64) {
    s += psum[p * F + c];
    q += psq[p * F + c];
  }
#pragma unroll
  for (int o = 1; o < 64; o <<= 1) {
    s += __shfl_xor(s, o, 64);
    q += __shfl_xor(q, o, 64);
  }
  if (lane == 0) {
    double inv_n = 1.0 / (double)n;
    double mu = s * inv_n;
    double var = q * inv_n - mu * mu;
    if (var < 0.) var = 0.;
    double istd = 1.0 / sqrt(var + 1e-5);
    double sc = istd * (double)g[c];
    double sh = (double)be[c] - mu * sc;
    scd[c] = sc;
    shd[c] = sh;
    scf[c] = (float)sc;
    shf[c] = (float)sh;
  }
}

// fp64 per-row dots with wrel/wroot (READ-ONLY)
__global__ __launch_bounds__(256) void score_dots(
    const float* __restrict__ hx,
    const double* __restrict__ scd, const double* __restrict__ shd,
    const float* __restrict__ wrel, const float* __restrict__ wroot,
    double* __restrict__ t, double* __restrict__ r, int F, int n) {
  int row = blockIdx.x * 4 + (threadIdx.x >> 6);
  if (row >= n) return;
  int lane = threadIdx.x & 63;
  int nf4 = F >> 2;
  const f32x4* hp = (const f32x4*)(hx + (size_t)row * F);
  double dr = 0., dq = 0.;
  for (int j = lane; j < nf4; j += 64) {
    f32x4 hv = hp[j];
#pragma unroll
    for (int c = 0; c < 4; ++c) {
      double vd = (double)hv[c] * scd[j * 4 + c] + shd[j * 4 + c];
      vd = vd > 0. ? vd : 0.;
      dr += vd * (double)wrel[j * 4 + c];
      dq += vd * (double)wroot[j * 4 + c];
    }
  }
#pragma unroll
  for (int o = 1; o < 64; o <<= 1) {
    dr += __shfl_xor(dr, o, 64);
    dq += __shfl_xor(dq, o, 64);
  }
  if (lane == 0) { t[row] = dr; r[row] = dq; }
}

// ---------------- fused score + per-graph top-k (radix-select, LDS scores) ----------------
// scores computed in-block into LDS (sorted-bucket order => deterministic),
// then radix-select + stable index-order compaction.
__global__ __launch_bounds__(1024) void topk_select(
    const int* __restrict__ offs, const int* __restrict__ esrc,
    const double* __restrict__ t, const double* __restrict__ r,
    const float* __restrict__ brel, int n_pg, int k,
    int* __restrict__ perm, float* __restrict__ tanhv, int* __restrict__ inv) {
  __shared__ double sscore[4096];
  __shared__ unsigned hist[256];
  __shared__ unsigned long long sPfx;
  __shared__ int sRem;
  __shared__ unsigned wsum[16];
  __shared__ unsigned woff[4];
  int g = blockIdx.x;
  int tid = threadIdx.x;
  double bb = (double)brel[0];
  // compute scores into LDS (fixed per-node edge order)
  for (int i = tid; i < n_pg; i += 1024) {
    int gi = g * n_pg + i;
    double acc = 0.;
    int e0 = offs[gi], e1 = offs[gi + 1];
    for (int e = e0; e < e1; ++e) acc += t[esrc[e]];
    sscore[i] = acc + r[gi] + bb;
  }
  __syncthreads();
  auto keyof = [&](int i) -> unsigned long long {
    unsigned long long u = (unsigned long long)__double_as_longlong(sscore[i]);
    u = (u >> 63) ? ~u : (u | 0x8000000000000000ULL);
    return ((u >> 12) << 12) | (unsigned long long)(4095 - i);
  };
  unsigned long long prefix = 0;
  int rem = k;
  for (int shift = 56; shift >= 0; shift -= 8) {
    if (tid < 256) hist[tid] = 0;
    __syncthreads();
    unsigned long long himask = (shift == 56) ? 0ULL : (~0ULL << (shift + 8));
    for (int i = tid; i < n_pg; i += 1024) {
      unsigned long long kk = keyof(i);
      if ((kk & himask) == prefix) {
        unsigned b = (unsigned)((kk >> shift) & 255);
        atomicAdd(&hist[b], 1u);
      }
    }
    __syncthreads();
    unsigned a = 0, v = 0;
    int slane = 0, swid = 0;
    if (tid < 256) {
      int rrev = 255 - tid;
      a = hist[tid];
      v = a;
      slane = rrev & 63;
      swid = rrev >> 6;
      for (int o = 1; o < 64; o <<= 1) {
        unsigned u2 = __shfl_down(v, o, 64);
        if (slane >= o) v += u2;
      }
      if (slane == 63) woff[swid] = v;
    }
    __syncthreads();
    if (tid < 256) {
      unsigned base2 = 0;
      for (int wi = 0; wi < swid; ++wi) base2 += woff[wi];
      unsigned Sinc = base2 + v;
      unsigned Sexc = Sinc - a;
      if ((int)Sexc < rem && (int)Sinc >= rem) {
        sPfx = prefix | (((unsigned long long)tid) << shift);
        sRem = rem - (int)Sexc;
      }
    }
    __syncthreads();
    prefix = sPfx;
    rem = sRem;
    __syncthreads();
  }
  unsigned long long Kstar = prefix;
  // stable compaction in index order
  int c = (n_pg + 1023) / 1024;
  int base = tid * c;
  int loc[4];
  int cnt = 0;
#pragma unroll 4
  for (int j = 0; j < c; ++j) {
    int i = base + j;
    int sel = (i < n_pg && keyof(i) >= Kstar) ? 1 : 0;
    loc[j] = cnt;
    cnt += sel;
  }
  int lane = tid & 63, wid = tid >> 6;
  int v2 = cnt;
  for (int o = 1; o < 64; o <<= 1) {
    int u2 = __shfl_up(v2, o, 64);
    if (lane >= o) v2 += u2;
  }
  int wexcl = v2 - cnt;
  if (lane == 63) wsum[wid] = (unsigned)v2;
  __syncthreads();
  if (tid == 0) {
    unsigned run = 0;
    for (int wi = 0; wi < 16; ++wi) { unsigned t2 = wsum[wi]; wsum[wi] = run; run += t2; }
  }
  __syncthreads();
  int offset = (int)wsum[wid] + wexcl;
  for (int j = 0; j < c; ++j) {
    int i = base + j;
    if (i >= n_pg) break;
    bool sel = keyof(i) >= Kstar;
    int old_g = g * n_pg + i;
    if (sel) {
      int new_g = g * k + offset + loc[j];
      perm[new_g] = old_g;
      tanhv[new_g] = (float)tanh(sscore[i]);
      inv[old_g] = new_g;
    } else {
      inv[old_g] = -1;
    }
  }
}

// gather kept rows; apply BN scale/shift + relu + tanh, emit 3-chunk bf16
__global__ __launch_bounds__(256) void gather_split(
    const float* __restrict__ h, const int* __restrict__ perm,
    const float* __restrict__ tanhv,
    const float* __restrict__ scf, const float* __restrict__ shf,
    short* __restrict__ gh, short* __restrict__ gm,
    short* __restrict__ gl, int F, int nk) {
  int i = blockIdx.x * 4 + (threadIdx.x >> 6);
  if (i >= nk) return;
  int lane = threadIdx.x & 63;
  int nf4 = F >> 2;
  int p = perm[i];
  float tv = tanhv[i];
  const f32x4* hp = (const f32x4*)(h + (size_t)p * F);
  const f32x4* sc = (const f32x4*)scf;
  const f32x4* sh = (const f32x4*)shf;
  for (int j = lane; j < nf4; j += 64) {
    f32x4 v = hp[j] * sc[j] + sh[j];
#pragma unroll
    for (int c = 0; c < 4; ++c) v[c] = fmaxf(v[c], 0.f);
    v *= tv;
    short hh[4], mm[4], ll[4];
#pragma unroll
    for (int c = 0; c < 4; ++c) split3(v[c], hh[c], mm[c], ll[c]);
    *(s16x4*)&gh[(size_t)i * F + j * 4] = *(s16x4*)hh;
    *(s16x4*)&gm[(size_t)i * F + j * 4] = *(s16x4*)mm;
    *(s16x4*)&gl[(size_t)i * F + j * 4] = *(s16x4*)ll;
  }
}

// remap edges to new ids + count next-layer in-degrees (int atomics: deterministic)
__global__ void remap_kernel(const int* __restrict__ src_in, const int* __restrict__ dst_in,
                             const int* __restrict__ inv, int* __restrict__ src_out,
                             int* __restrict__ dst_out, int* __restrict__ cnt, int E) {
  int e = blockIdx.x * 256 + threadIdx.x;
  if (e >= E) return;
  int d = dst_in[e];
  int ns = -1, nd = -1;
  if (d >= 0) { ns = inv[src_in[e]]; nd = inv[d]; }
  if (ns >= 0 && nd >= 0) {
    src_out[e] = ns;
    dst_out[e] = nd;
    atomicAdd(&cnt[nd], 1);
  } else {
    src_out[e] = 0;
    dst_out[e] = -1;
  }
}

// ---------------- final global mean+max pool (two stage) ----------------
#define PCH 16
__global__ void pool_partial(const float* __restrict__ h, float* __restrict__ part,
                             int k3, int F) {
  int g = blockIdx.x, c = blockIdx.y;
  int tid = threadIdx.x;
  int chunk = (k3 + PCH - 1) / PCH;
  int r0 = c * chunk, r1 = min(r0 + chunk, k3);
  const float* base = h + (size_t)g * k3 * F;
  float sm = 0.f, mx = -INFINITY;
  for (int r = r0; r < r1; ++r) {
    float v = base[(size_t)r * F + tid];
    sm += v;
    mx = fmaxf(mx, v);
  }
  float* pp = part + (size_t)(g * PCH + c) * 2 * F;
  pp[tid] = sm;
  pp[F + tid] = mx;
}
__global__ void pool_final(const float* __restrict__ part, float* __restrict__ out,
                           int k3, int F) {
  int g = blockIdx.x;
  int tid = threadIdx.x;
  float sm = 0.f, mx = -INFINITY;
  for (int c = 0; c < PCH; ++c) {
    const float* pp = part + (size_t)(g * PCH + c) * 2 * F;
    sm += pp[tid];
    mx = fmaxf(mx, pp[F + tid]);
  }
  out[g * F + tid] = sm / (float)k3 + mx;
}

extern "C" void kernel_launch(void* const* d_in, const int* in_sizes, int n_in,
                              void* d_out, int out_size, void* d_ws, size_t ws_size,
                              hipStream_t stream) {
  const float* x0 = (const float*)d_in[0];
  const int* eidx = (const int*)d_in[1];
  const float* W1 = (const float*)d_in[2];  const float* b1 = (const float*)d_in[3];
  const float* W2 = (const float*)d_in[4];  const float* b2 = (const float*)d_in[5];
  const float* W3 = (const float*)d_in[6];  const float* b3 = (const float*)d_in[7];
  const float* W4 = (const float*)d_in[8];  const float* b4 = (const float*)d_in[9];
  const float* g1 = (const float*)d_in[10]; const float* be1 = (const float*)d_in[11];
  const float* g2 = (const float*)d_in[12]; const float* be2 = (const float*)d_in[13];
  const float* g3 = (const float*)d_in[14]; const float* be3 = (const float*)d_in[15];
  const float* p1r = (const float*)d_in[16]; const float* p1b = (const float*)d_in[17];
  const float* p1o = (const float*)d_in[18];
  const float* p2r = (const float*)d_in[19]; const float* p2b = (const float*)d_in[20];
  const float* p2o = (const float*)d_in[21];
  const float* p3r = (const float*)d_in[22]; const float* p3b = (const float*)d_in[23];
  const float* p3o = (const float*)d_in[24];

  char* w = (char*)d_ws;
  size_t off = 0;
  auto alloc = [&](size_t bytes) -> void* {
    void* p = w + off;
    off = (off + bytes + 255) & ~(size_t)255;
    return p;
  };
  float* BUF0 = (float*)alloc(32768ull * 512 * 4);
  float* BUF1 = (float*)alloc(19664ull * 512 * 4);
  short* XH = (short*)alloc(32768ull * 384 * 2);
  short* XM = (short*)alloc(32768ull * 384 * 2);
  short* XL = (short*)alloc(32768ull * 384 * 2);
  short* WTH = (short*)alloc(638976ull * 2);
  short* WTM = (short*)alloc(638976ull * 2);
  short* WTL = (short*)alloc(638976ull * 2);
  int* czone = (int*)alloc(65537ull * 4);
  int* cnt = czone;
  int* tmpc = czone + 32769;
  int* offs = (int*)alloc(32769 * 4);
  float* dis = (float*)alloc(32768 * 4);
  double* tvec = (double*)alloc(32768 * 8);
  double* rvec = (double*)alloc(32768 * 8);
  int* inv = (int*)alloc(32768 * 4);
  int* perm = (int*)alloc(32768 * 4);
  float* tanhv = (float*)alloc(32768 * 4);
  int* e0s = (int*)alloc(E_TOTAL * 4);
  int* e0d = (int*)alloc(E_TOTAL * 4);
  int* e1s = (int*)alloc(E_TOTAL * 4);
  int* e1d = (int*)alloc(E_TOTAL * 4);
  int* esrc = (int*)alloc(E_TOTAL * 4);
  double* bnsum = (double*)alloc((size_t)BNY * 512 * 8);
  double* bnsq = (double*)alloc((size_t)BNY * 512 * 8);
  float* bnscf = (float*)alloc(512 * 4);
  float* bnshf = (float*)alloc(512 * 4);
  double* bnscd = (double*)alloc(512 * 8);
  double* bnshd = (double*)alloc(512 * 8);
  float* part = (float*)alloc((size_t)NB * PCH * 2 * 192 * 4);

  const int EB = cdiv(E_TOTAL, 256);

  auto build_csr = [&](const int* src, const int* dst, int n) {
    scan_kernel<<<1, 1024, 0, stream>>>(cnt, offs, dis, n);
    scatter_kernel<<<EB, 256, 0, stream>>>(src, dst, offs, tmpc, esrc, E_TOTAL);
    sort_buckets<<<cdiv(n, 256), 256, 0, stream>>>(offs, esrc, n);
  };

  auto pool = [&](float* hbuf, int n, int n_pg, int k, int F,
                  const float* g, const float* be, const float* wr, const float* wb,
                  const float* wo, const int* src, const int* dst, int* nsrc, int* ndst) {
    bn_stats_part<<<dim3(cdiv(F, 256), BNY), 256, 0, stream>>>(hbuf, bnsum, bnsq, n, F);
    bn_reduce<<<F, 64, 0, stream>>>(bnsum, bnsq, g, be, bnscf, bnshf, bnscd, bnshd, n, F);
    score_dots<<<cdiv(n, 4), 256, 0, stream>>>(hbuf, bnscd, bnshd, wr, wo, tvec, rvec, F, n);
    topk_select<<<NB, 1024, 0, stream>>>(offs, esrc, tvec, rvec, wb, n_pg, k, perm, tanhv, inv);
    gather_split<<<cdiv(NB * k, 4), 256, 0, stream>>>(hbuf, perm, tanhv, bnscf, bnshf, XH, XM, XL, F, NB * k);
    fill_i32<<<cdiv(65537, 256), 256, 0, stream>>>(czone, 0, 65537);
    remap_kernel<<<EB, 256, 0, stream>>>(src, dst, inv, nsrc, ndst, cnt, E_TOTAL);
  };

  // weight split+transpose (3x bf16)
  split_w_t<<<cdiv(384 * 512, 256), 256, 0, stream>>>(W1, WTH, WTM, WTL, 384, 512);
  split_w_t<<<cdiv(512 * 512, 256), 256, 0, stream>>>(W2, WTH + 196608, WTM + 196608, WTL + 196608, 512, 512);
  split_w_t<<<cdiv(512 * 256, 256), 256, 0, stream>>>(W3, WTH + 458752, WTM + 458752, WTL + 458752, 512, 256);
  split_w_t<<<cdiv(256 * 192, 256), 256, 0, stream>>>(W4, WTH + 589824, WTM + 589824, WTL + 589824, 256, 192);

  // ---- Layer 1
  fill_i32<<<cdiv(65537, 256), 256, 0, stream>>>(czone, 0, 65537);
  count_kernel<<<EB, 256, 0, stream>>>(eidx + E_TOTAL, cnt, E_TOTAL);
  build_csr(eidx, eidx + E_TOTAL, 32768);
  agg_kernel<<<cdiv(32768, 4), 256, 0, stream>>>(x0, offs, esrc, dis, nullptr, nullptr, XH, XM, XL, 384, 32768);
  gemm_mfma<<<cdiv(32768, 128) * 2, 512, 0, stream>>>(XH, XM, XL, WTH, WTM, WTL, b1, BUF0, 32768, 384, 512, 2);
  pool(BUF0, 32768, 4096, 2458, 512, g1, be1, p1r, p1b, p1o, eidx, eidx + E_TOTAL, e0s, e0d);

  // ---- Layer 2
  build_csr(e0s, e0d, 19664);
  gemm_mfma<<<cdiv(19664, 128) * 2, 512, 0, stream>>>(XH, XM, XL, WTH + 196608, WTM + 196608, WTL + 196608, nullptr, BUF0, 19664, 512, 512, 2);
  agg_kernel<<<cdiv(19664, 4), 256, 0, stream>>>(BUF0, offs, esrc, dis, b2, BUF1, nullptr, nullptr, nullptr, 512, 19664);
  pool(BUF1, 19664, 2458, 1475, 512, g2, be2, p2r, p2b, p2o, e0s, e0d, e1s, e1d);

  // ---- Layer 3
  build_csr(e1s, e1d, 11800);
  gemm_mfma<<<cdiv(11800, 128), 512, 0, stream>>>(XH, XM, XL, WTH + 458752, WTM + 458752, WTL + 458752, nullptr, BUF0, 11800, 512, 256, 1);
  agg_kernel<<<cdiv(11800, 4), 256, 0, stream>>>(BUF0, offs, esrc, dis, b3, BUF1, nullptr, nullptr, nullptr, 256, 11800);
  pool(BUF1, 11800, 1475, 738, 256, g3, be3, p3r, p3b, p3o, e1s, e1d, e0s, e0d);

  // ---- Layer 4
  build_csr(e0s, e0d, 5904);
  gemm_mfma<<<cdiv(5904, 128), 512, 0, stream>>>(XH, XM, XL, WTH + 589824, WTM + 589824, WTL + 589824, nullptr, BUF0, 5904, 256, 192, 1);
  agg_kernel<<<cdiv(5904, 4), 256, 0, stream>>>(BUF0, offs, esrc, dis, b4, BUF1, nullptr, nullptr, nullptr, 192, 5904);
  pool_partial<<<dim3(NB, PCH), 192, 0, stream>>>(BUF1, part, 738, 192);
  pool_final<<<NB, 192, 0, stream>>>(part, (float*)d_out, 738, 192);
}

// Round 19
// 1007.498 us; speedup vs baseline: 1.0228x; 1.0228x over previous
//
#include <hip/hip_runtime.h>
#include <cmath>

#define E_TOTAL 524288
#define NB 8

using f32x4 = __attribute__((ext_vector_type(4))) float;
using s16x8 = __attribute__((ext_vector_type(8))) short;
using s16x4 = __attribute__((ext_vector_type(4))) short;

static inline int cdiv(int a, int b) { return (a + b - 1) / b; }

__device__ inline unsigned short bf16_rn(float x) {
  unsigned u = __float_as_uint(x);
  return (unsigned short)((u + 0x7FFFu + ((u >> 16) & 1u)) >> 16);
}
// 3-chunk split: x ~= h + m + l with residual ~2^-24 |x|
__device__ inline void split3(float x, short& h, short& m, short& l) {
  unsigned short hb = bf16_rn(x);
  h = (short)hb;
  float hf = __uint_as_float(((unsigned)hb) << 16);
  float r1 = x - hf;
  unsigned short mb = bf16_rn(r1);
  m = (short)mb;
  float mf = __uint_as_float(((unsigned)mb) << 16);
  l = (short)bf16_rn(r1 - mf);
}

// async global->LDS 16B copy. LDS dest must be WAVE-UNIFORM; HW adds lane*16.
__device__ inline void async_copy16(const short* g, short* l) {
  __builtin_amdgcn_global_load_lds(
      (const __attribute__((address_space(1))) void*)(unsigned long long)(g),
      (__attribute__((address_space(3))) void*)(unsigned)(unsigned long long)(l),
      16, 0, 0);
}

// ---------------- fills ----------------
__global__ void fill_i32(int* p, int v, int n) {
  int i = blockIdx.x * 256 + threadIdx.x;
  if (i < n) p[i] = v;
}

// ---------------- weight split + transpose: W[K][N] fp32 -> WT[N][K] 3x bf16 ----------------
__global__ void split_w_t(const float* __restrict__ W, short* __restrict__ TH,
                          short* __restrict__ TM, short* __restrict__ TL, int K, int N) {
  int i = blockIdx.x * 256 + threadIdx.x;
  if (i >= K * N) return;
  int k = i / N, n = i % N;
  short h, m, l;
  split3(W[i], h, m, l);
  TH[(size_t)n * K + k] = h;
  TM[(size_t)n * K + k] = m;
  TL[(size_t)n * K + k] = l;
}

// ---------------- 3-chunk split-bf16 MFMA GEMM, double-buffered async LDS ----------------
// (round-16 proven structure: __syncthreads-based dbuf; compiler schedules
// waitcnts. Counted-vmcnt + sched_barrier variant regressed — reverted.)
#define GBM 128
#define GBN 256
#define GBK 32
#define BUFS 36864
#define BOFF 12288

__global__ __launch_bounds__(512) void gemm_mfma(
    const short* __restrict__ AH, const short* __restrict__ AM, const short* __restrict__ AL,
    const short* __restrict__ BH, const short* __restrict__ BM, const short* __restrict__ BL,
    const float* __restrict__ bias, float* __restrict__ C,
    int M, int K, int N, int nblocks) {
  __shared__ __align__(16) short lds[2][BUFS];
  int nwg = gridDim.x;
  int orig = blockIdx.x;
  int q = nwg >> 3, r = nwg & 7;
  int xc = orig & 7, j8 = orig >> 3;
  int wg = (xc < r ? xc * (q + 1) : r * (q + 1) + (xc - r) * q) + j8;
  int bm = (wg / nblocks) * GBM;
  int bn = (wg % nblocks) * GBN;
  int tid = threadIdx.x;
  int wave = tid >> 6, lane = tid & 63;
  int wr = wave >> 2, wc = wave & 3;
  int l15 = lane & 15, l4 = lane >> 4;
  int pa = wave * 64 + lane;
  int ra = pa >> 2, ca = (pa & 3) ^ ((ra >> 1) & 3);
  int gar = bm + ra; gar = gar < M ? gar : 0;
  size_t gaoff = (size_t)gar * K + ca * 8;
  int adest = wave * 512;
  int pb0 = wave * 128 + lane, pb1 = pb0 + 64;
  int rb0 = pb0 >> 2, cb0 = (pb0 & 3) ^ ((rb0 >> 1) & 3);
  int rb1 = pb1 >> 2, cb1 = (pb1 & 3) ^ ((rb1 >> 1) & 3);
  int gbr0 = bn + rb0; gbr0 = gbr0 < N ? gbr0 : 0;
  int gbr1 = bn + rb1; gbr1 = gbr1 < N ? gbr1 : 0;
  size_t gboff0 = (size_t)gbr0 * K + cb0 * 8;
  size_t gboff1 = (size_t)gbr1 * K + cb1 * 8;
  int bdest = BOFF + wave * 1024;

  auto stage = [&](int b, int k0) {
    short* base = lds[b];
    async_copy16(AH + gaoff + k0, base + adest);
    async_copy16(AM + gaoff + k0, base + 4096 + adest);
    async_copy16(AL + gaoff + k0, base + 8192 + adest);
    async_copy16(BH + gboff0 + k0, base + bdest);
    async_copy16(BH + gboff1 + k0, base + bdest + 512);
    async_copy16(BM + gboff0 + k0, base + 8192 + bdest);
    async_copy16(BM + gboff1 + k0, base + 8192 + bdest + 512);
    async_copy16(BL + gboff0 + k0, base + 16384 + bdest);
    async_copy16(BL + gboff1 + k0, base + 16384 + bdest + 512);
  };

  f32x4 acc[4][4] = {};
  int cur = 0;
  stage(0, 0);
  __syncthreads();
  for (int k0 = 0; k0 < K; k0 += GBK) {
    if (k0 + GBK < K) stage(cur ^ 1, k0 + GBK);
    const short* base = lds[cur];
    s16x8 fah[4], fam[4], fal[4], fbh[4], fbm[4], fbl[4];
#pragma unroll
    for (int mi = 0; mi < 4; ++mi) {
      int row = wr * 64 + mi * 16 + l15;
      int ad = row * 32 + ((l4 ^ ((row >> 1) & 3)) << 3);
      fah[mi] = *(const s16x8*)(base + ad);
      fam[mi] = *(const s16x8*)(base + 4096 + ad);
      fal[mi] = *(const s16x8*)(base + 8192 + ad);
    }
#pragma unroll
    for (int ni = 0; ni < 4; ++ni) {
      int row = wc * 64 + ni * 16 + l15;
      int bd = BOFF + row * 32 + ((l4 ^ ((row >> 1) & 3)) << 3);
      fbh[ni] = *(const s16x8*)(base + bd);
      fbm[ni] = *(const s16x8*)(base + 8192 + bd);
      fbl[ni] = *(const s16x8*)(base + 16384 + bd);
    }
#pragma unroll
    for (int mi = 0; mi < 4; ++mi)
#pragma unroll
      for (int ni = 0; ni < 4; ++ni) {
        acc[mi][ni] = __builtin_amdgcn_mfma_f32_16x16x32_bf16(fah[mi], fbh[ni], acc[mi][ni], 0, 0, 0);
        acc[mi][ni] = __builtin_amdgcn_mfma_f32_16x16x32_bf16(fah[mi], fbm[ni], acc[mi][ni], 0, 0, 0);
        acc[mi][ni] = __builtin_amdgcn_mfma_f32_16x16x32_bf16(fam[mi], fbh[ni], acc[mi][ni], 0, 0, 0);
        acc[mi][ni] = __builtin_amdgcn_mfma_f32_16x16x32_bf16(fah[mi], fbl[ni], acc[mi][ni], 0, 0, 0);
        acc[mi][ni] = __builtin_amdgcn_mfma_f32_16x16x32_bf16(fal[mi], fbh[ni], acc[mi][ni], 0, 0, 0);
        acc[mi][ni] = __builtin_amdgcn_mfma_f32_16x16x32_bf16(fam[mi], fbm[ni], acc[mi][ni], 0, 0, 0);
      }
    __syncthreads();
    cur ^= 1;
  }
#pragma unroll
  for (int ni = 0; ni < 4; ++ni) {
    int col = bn + wc * 64 + ni * 16 + l15;
    if (col >= N) continue;
    float bv = bias ? bias[col] : 0.f;
#pragma unroll
    for (int mi = 0; mi < 4; ++mi) {
      int row0 = bm + wr * 64 + mi * 16 + l4 * 4;
#pragma unroll
      for (int rr = 0; rr < 4; ++rr) {
        int row = row0 + rr;
        if (row < M) C[(size_t)row * N + col] = acc[mi][ni][rr] + bv;
      }
    }
  }
}

// ---------------- CSR build ----------------
__global__ void count_kernel(const int* __restrict__ dst, int* __restrict__ cnt, int E) {
  int e = blockIdx.x * 256 + threadIdx.x;
  if (e >= E) return;
  atomicAdd(&cnt[dst[e]], 1);
}

// scan + fused dis computation
__global__ __launch_bounds__(1024) void scan_kernel(const int* __restrict__ cnt,
                                                    int* __restrict__ offs,
                                                    float* __restrict__ dis, int n) {
  __shared__ int tsum[1024];
  int tid = threadIdx.x;
  int chunk = (n + 1023) / 1024;
  int base = tid * chunk;
  int lsum = 0;
  for (int i = 0; i < chunk; ++i) {
    int idx = base + i;
    if (idx < n) lsum += cnt[idx];
  }
  tsum[tid] = lsum;
  __syncthreads();
  for (int off = 1; off < 1024; off <<= 1) {
    int add = (tid >= off) ? tsum[tid - off] : 0;
    __syncthreads();
    tsum[tid] += add;
    __syncthreads();
  }
  int run = (tid == 0) ? 0 : tsum[tid - 1];
  for (int i = 0; i < chunk; ++i) {
    int idx = base + i;
    if (idx < n) {
      offs[idx] = run;
      int c = cnt[idx];
      run += c;
      dis[idx] = (c > 0) ? (float)(1.0 / sqrt((double)c)) : 0.f;
    }
  }
  if (tid == 1023) offs[n] = run;
}

__global__ void scatter_kernel(const int* __restrict__ src, const int* __restrict__ dst,
                               const int* __restrict__ offs, int* __restrict__ tmpc,
                               int* __restrict__ esrc, int E) {
  int e = blockIdx.x * 256 + threadIdx.x;
  if (e >= E) return;
  int d = dst[e];
  if (d < 0) return;
  int pos = offs[d] + atomicAdd(&tmpc[d], 1);
  esrc[pos] = src[e];
}

// canonicalize bucket order (determinism)
__global__ void sort_buckets(const int* __restrict__ offs, int* __restrict__ esrc, int n) {
  int node = blockIdx.x * 256 + threadIdx.x;
  if (node >= n) return;
  int s0 = offs[node], s1 = offs[node + 1];
  for (int i = s0 + 1; i < s1; ++i) {
    int v = esrc[i];
    int j = i - 1;
    while (j >= s0 && esrc[j] > v) { esrc[j + 1] = esrc[j]; --j; }
    esrc[j + 1] = v;
  }
}

// ---------------- aggregation (wave per node, f32x4, 4-way edge unroll) ----------------
__global__ __launch_bounds__(256) void agg_kernel(
    const float* __restrict__ h, const int* __restrict__ offs,
    const int* __restrict__ esrc, const float* __restrict__ dis,
    const float* __restrict__ bias, float* __restrict__ outf,
    short* __restrict__ outh, short* __restrict__ outm, short* __restrict__ outl,
    int F, int n) {
  int node = blockIdx.x * 4 + (threadIdx.x >> 6);
  if (node >= n) return;
  int lane = threadIdx.x & 63;
  int nf4 = F >> 2;
  int i0 = lane, i1 = lane + 64;
  bool a0 = i0 < nf4, a1 = i1 < nf4;
  f32x4 acc0 = {}, acc1 = {};
  int e0 = offs[node], e1 = offs[node + 1];
  int e = e0;
  for (; e + 4 <= e1; e += 4) {
    int s0 = esrc[e], s1 = esrc[e + 1], s2 = esrc[e + 2], s3 = esrc[e + 3];
    float w0 = dis[s0], w1 = dis[s1], w2 = dis[s2], w3 = dis[s3];
    const f32x4* p0 = (const f32x4*)(h + (size_t)s0 * F);
    const f32x4* p1 = (const f32x4*)(h + (size_t)s1 * F);
    const f32x4* p2 = (const f32x4*)(h + (size_t)s2 * F);
    const f32x4* p3 = (const f32x4*)(h + (size_t)s3 * F);
    if (a0) {
      f32x4 v0 = p0[i0], v1 = p1[i0], v2 = p2[i0], v3 = p3[i0];
      acc0 += v0 * w0;
      acc0 += v1 * w1;
      acc0 += v2 * w2;
      acc0 += v3 * w3;
    }
    if (a1) {
      f32x4 v0 = p0[i1], v1 = p1[i1], v2 = p2[i1], v3 = p3[i1];
      acc1 += v0 * w0;
      acc1 += v1 * w1;
      acc1 += v2 * w2;
      acc1 += v3 * w3;
    }
  }
  for (; e < e1; ++e) {
    int s = esrc[e];
    float w = dis[s];
    const f32x4* hp = (const f32x4*)(h + (size_t)s * F);
    if (a0) acc0 += hp[i0] * w;
    if (a1) acc1 += hp[i1] * w;
  }
  float wd = dis[node];
  acc0 *= wd;
  acc1 *= wd;
  if (outf) {
    const f32x4* b4 = (const f32x4*)bias;
    f32x4* op = (f32x4*)(outf + (size_t)node * F);
    if (a0) op[i0] = acc0 + b4[i0];
    if (a1) op[i1] = acc1 + b4[i1];
  } else {
    short hh[4], mm[4], ll[4];
    if (a0) {
#pragma unroll
      for (int c = 0; c < 4; ++c) split3(acc0[c], hh[c], mm[c], ll[c]);
      *(s16x4*)&outh[(size_t)node * F + i0 * 4] = *(s16x4*)hh;
      *(s16x4*)&outm[(size_t)node * F + i0 * 4] = *(s16x4*)mm;
      *(s16x4*)&outl[(size_t)node * F + i0 * 4] = *(s16x4*)ll;
    }
    if (a1) {
#pragma unroll
      for (int c = 0; c < 4; ++c) split3(acc1[c], hh[c], mm[c], ll[c]);
      *(s16x4*)&outh[(size_t)node * F + i1 * 4] = *(s16x4*)hh;
      *(s16x4*)&outm[(size_t)node * F + i1 * 4] = *(s16x4*)mm;
      *(s16x4*)&outl[(size_t)node * F + i1 * 4] = *(s16x4*)ll;
    }
  }
}

// ---------------- batch norm (two-stage fp64, atomic-free, deterministic) ----------------
#define BNY 512
__global__ void bn_stats_part(const float* __restrict__ x, double* __restrict__ psum,
                              double* __restrict__ psq, int n, int F) {
  int col = blockIdx.x * 256 + threadIdx.x;
  if (col >= F) return;
  double s = 0., q = 0.;
  for (int r = blockIdx.y; r < n; r += gridDim.y) {
    double v = (double)x[(size_t)r * F + col];
    s += v;
    q += v * v;
  }
  psum[blockIdx.y * F + col] = s;
  psq[blockIdx.y * F + col] = q;
}

// one block per column, 64-thread tree reduce (fixed order => deterministic)
__global__ __launch_bounds__(64) void bn_reduce(
    const double* __restrict__ psum, const double* __restrict__ psq,
    const float* __restrict__ g, const float* __restrict__ be,
    float* __restrict__ scf, float* __restrict__ shf,
    double* __restrict__ scd, double* __restrict__ shd, int n, int F) {
  int c = blockIdx.x;
  int lane = threadIdx.x;
  double s = 0., q = 0.;
  for (int p = lane; p < BNY; p += 64) {
    s += psum[p * F + c];
    q += psq[p * F + c];
  }
#pragma unroll
  for (int o = 1; o < 64; o <<= 1) {
    s += __shfl_xor(s, o, 64);
    q += __shfl_xor(q, o, 64);
  }
  if (lane == 0) {
    double inv_n = 1.0 / (double)n;
    double mu = s * inv_n;
    double var = q * inv_n - mu * mu;
    if (var < 0.) var = 0.;
    double istd = 1.0 / sqrt(var + 1e-5);
    double sc = istd * (double)g[c];
    double sh = (double)be[c] - mu * sc;
    scd[c] = sc;
    shd[c] = sh;
    scf[c] = (float)sc;
    shf[c] = (float)sh;
  }
}

// fp64 per-row dots with wrel/wroot (READ-ONLY)
__global__ __launch_bounds__(256) void score_dots(
    const float* __restrict__ hx,
    const double* __restrict__ scd, const double* __restrict__ shd,
    const float* __restrict__ wrel, const float* __restrict__ wroot,
    double* __restrict__ t, double* __restrict__ r, int F, int n) {
  int row = blockIdx.x * 4 + (threadIdx.x >> 6);
  if (row >= n) return;
  int lane = threadIdx.x & 63;
  int nf4 = F >> 2;
  const f32x4* hp = (const f32x4*)(hx + (size_t)row * F);
  double dr = 0., dq = 0.;
  for (int j = lane; j < nf4; j += 64) {
    f32x4 hv = hp[j];
#pragma unroll
    for (int c = 0; c < 4; ++c) {
      double vd = (double)hv[c] * scd[j * 4 + c] + shd[j * 4 + c];
      vd = vd > 0. ? vd : 0.;
      dr += vd * (double)wrel[j * 4 + c];
      dq += vd * (double)wroot[j * 4 + c];
    }
  }
#pragma unroll
  for (int o = 1; o < 64; o <<= 1) {
    dr += __shfl_xor(dr, o, 64);
    dq += __shfl_xor(dq, o, 64);
  }
  if (lane == 0) { t[row] = dr; r[row] = dq; }
}

// ---------------- fused score + per-graph top-k (radix-select, LDS scores) ----------------
__global__ __launch_bounds__(1024) void topk_select(
    const int* __restrict__ offs, const int* __restrict__ esrc,
    const double* __restrict__ t, const double* __restrict__ r,
    const float* __restrict__ brel, int n_pg, int k,
    int* __restrict__ perm, float* __restrict__ tanhv, int* __restrict__ inv) {
  __shared__ double sscore[4096];
  __shared__ unsigned hist[256];
  __shared__ unsigned long long sPfx;
  __shared__ int sRem;
  __shared__ unsigned wsum[16];
  __shared__ unsigned woff[4];
  int g = blockIdx.x;
  int tid = threadIdx.x;
  double bb = (double)brel[0];
  for (int i = tid; i < n_pg; i += 1024) {
    int gi = g * n_pg + i;
    double acc = 0.;
    int e0 = offs[gi], e1 = offs[gi + 1];
    for (int e = e0; e < e1; ++e) acc += t[esrc[e]];
    sscore[i] = acc + r[gi] + bb;
  }
  __syncthreads();
  auto keyof = [&](int i) -> unsigned long long {
    unsigned long long u = (unsigned long long)__double_as_longlong(sscore[i]);
    u = (u >> 63) ? ~u : (u | 0x8000000000000000ULL);
    return ((u >> 12) << 12) | (unsigned long long)(4095 - i);
  };
  unsigned long long prefix = 0;
  int rem = k;
  for (int shift = 56; shift >= 0; shift -= 8) {
    if (tid < 256) hist[tid] = 0;
    __syncthreads();
    unsigned long long himask = (shift == 56) ? 0ULL : (~0ULL << (shift + 8));
    for (int i = tid; i < n_pg; i += 1024) {
      unsigned long long kk = keyof(i);
      if ((kk & himask) == prefix) {
        unsigned b = (unsigned)((kk >> shift) & 255);
        atomicAdd(&hist[b], 1u);
      }
    }
    __syncthreads();
    unsigned a = 0, v = 0;
    int slane = 0, swid = 0;
    if (tid < 256) {
      int rrev = 255 - tid;
      a = hist[tid];
      v = a;
      slane = rrev & 63;
      swid = rrev >> 6;
      for (int o = 1; o < 64; o <<= 1) {
        unsigned u2 = __shfl_down(v, o, 64);
        if (slane >= o) v += u2;
      }
      if (slane == 63) woff[swid] = v;
    }
    __syncthreads();
    if (tid < 256) {
      unsigned base2 = 0;
      for (int wi = 0; wi < swid; ++wi) base2 += woff[wi];
      unsigned Sinc = base2 + v;
      unsigned Sexc = Sinc - a;
      if ((int)Sexc < rem && (int)Sinc >= rem) {
        sPfx = prefix | (((unsigned long long)tid) << shift);
        sRem = rem - (int)Sexc;
      }
    }
    __syncthreads();
    prefix = sPfx;
    rem = sRem;
    __syncthreads();
  }
  unsigned long long Kstar = prefix;
  int c = (n_pg + 1023) / 1024;
  int base = tid * c;
  int loc[4];
  int cnt = 0;
#pragma unroll 4
  for (int j = 0; j < c; ++j) {
    int i = base + j;
    int sel = (i < n_pg && keyof(i) >= Kstar) ? 1 : 0;
    loc[j] = cnt;
    cnt += sel;
  }
  int lane = tid & 63, wid = tid >> 6;
  int v2 = cnt;
  for (int o = 1; o < 64; o <<= 1) {
    int u2 = __shfl_up(v2, o, 64);
    if (lane >= o) v2 += u2;
  }
  int wexcl = v2 - cnt;
  if (lane == 63) wsum[wid] = (unsigned)v2;
  __syncthreads();
  if (tid == 0) {
    unsigned run = 0;
    for (int wi = 0; wi < 16; ++wi) { unsigned t2 = wsum[wi]; wsum[wi] = run; run += t2; }
  }
  __syncthreads();
  int offset = (int)wsum[wid] + wexcl;
  for (int j = 0; j < c; ++j) {
    int i = base + j;
    if (i >= n_pg) break;
    bool sel = keyof(i) >= Kstar;
    int old_g = g * n_pg + i;
    if (sel) {
      int new_g = g * k + offset + loc[j];
      perm[new_g] = old_g;
      tanhv[new_g] = (float)tanh(sscore[i]);
      inv[old_g] = new_g;
    } else {
      inv[old_g] = -1;
    }
  }
}

// gather kept rows; apply BN scale/shift + relu + tanh, emit 3-chunk bf16
__global__ __launch_bounds__(256) void gather_split(
    const float* __restrict__ h, const int* __restrict__ perm,
    const float* __restrict__ tanhv,
    const float* __restrict__ scf, const float* __restrict__ shf,
    short* __restrict__ gh, short* __restrict__ gm,
    short* __restrict__ gl, int F, int nk) {
  int i = blockIdx.x * 4 + (threadIdx.x >> 6);
  if (i >= nk) return;
  int lane = threadIdx.x & 63;
  int nf4 = F >> 2;
  int p = perm[i];
  float tv = tanhv[i];
  const f32x4* hp = (const f32x4*)(h + (size_t)p * F);
  const f32x4* sc = (const f32x4*)scf;
  const f32x4* sh = (const f32x4*)shf;
  for (int j = lane; j < nf4; j += 64) {
    f32x4 v = hp[j] * sc[j] + sh[j];
#pragma unroll
    for (int c = 0; c < 4; ++c) v[c] = fmaxf(v[c], 0.f);
    v *= tv;
    short hh[4], mm[4], ll[4];
#pragma unroll
    for (int c = 0; c < 4; ++c) split3(v[c], hh[c], mm[c], ll[c]);
    *(s16x4*)&gh[(size_t)i * F + j * 4] = *(s16x4*)hh;
    *(s16x4*)&gm[(size_t)i * F + j * 4] = *(s16x4*)mm;
    *(s16x4*)&gl[(size_t)i * F + j * 4] = *(s16x4*)ll;
  }
}

// remap edges to new ids + count next-layer in-degrees (int atomics: deterministic)
__global__ void remap_kernel(const int* __restrict__ src_in, const int* __restrict__ dst_in,
                             const int* __restrict__ inv, int* __restrict__ src_out,
                             int* __restrict__ dst_out, int* __restrict__ cnt, int E) {
  int e = blockIdx.x * 256 + threadIdx.x;
  if (e >= E) return;
  int d = dst_in[e];
  int ns = -1, nd = -1;
  if (d >= 0) { ns = inv[src_in[e]]; nd = inv[d]; }
  if (ns >= 0 && nd >= 0) {
    src_out[e] = ns;
    dst_out[e] = nd;
    atomicAdd(&cnt[nd], 1);
  } else {
    src_out[e] = 0;
    dst_out[e] = -1;
  }
}

// ---------------- final global mean+max pool (two stage) ----------------
#define PCH 16
__global__ void pool_partial(const float* __restrict__ h, float* __restrict__ part,
                             int k3, int F) {
  int g = blockIdx.x, c = blockIdx.y;
  int tid = threadIdx.x;
  int chunk = (k3 + PCH - 1) / PCH;
  int r0 = c * chunk, r1 = min(r0 + chunk, k3);
  const float* base = h + (size_t)g * k3 * F;
  float sm = 0.f, mx = -INFINITY;
  for (int r = r0; r < r1; ++r) {
    float v = base[(size_t)r * F + tid];
    sm += v;
    mx = fmaxf(mx, v);
  }
  float* pp = part + (size_t)(g * PCH + c) * 2 * F;
  pp[tid] = sm;
  pp[F + tid] = mx;
}
__global__ void pool_final(const float* __restrict__ part, float* __restrict__ out,
                           int k3, int F) {
  int g = blockIdx.x;
  int tid = threadIdx.x;
  float sm = 0.f, mx = -INFINITY;
  for (int c = 0; c < PCH; ++c) {
    const float* pp = part + (size_t)(g * PCH + c) * 2 * F;
    sm += pp[tid];
    mx = fmaxf(mx, pp[F + tid]);
  }
  out[g * F + tid] = sm / (float)k3 + mx;
}

extern "C" void kernel_launch(void* const* d_in, const int* in_sizes, int n_in,
                              void* d_out, int out_size, void* d_ws, size_t ws_size,
                              hipStream_t stream) {
  const float* x0 = (const float*)d_in[0];
  const int* eidx = (const int*)d_in[1];
  const float* W1 = (const float*)d_in[2];  const float* b1 = (const float*)d_in[3];
  const float* W2 = (const float*)d_in[4];  const float* b2 = (const float*)d_in[5];
  const float* W3 = (const float*)d_in[6];  const float* b3 = (const float*)d_in[7];
  const float* W4 = (const float*)d_in[8];  const float* b4 = (const float*)d_in[9];
  const float* g1 = (const float*)d_in[10]; const float* be1 = (const float*)d_in[11];
  const float* g2 = (const float*)d_in[12]; const float* be2 = (const float*)d_in[13];
  const float* g3 = (const float*)d_in[14]; const float* be3 = (const float*)d_in[15];
  const float* p1r = (const float*)d_in[16]; const float* p1b = (const float*)d_in[17];
  const float* p1o = (const float*)d_in[18];
  const float* p2r = (const float*)d_in[19]; const float* p2b = (const float*)d_in[20];
  const float* p2o = (const float*)d_in[21];
  const float* p3r = (const float*)d_in[22]; const float* p3b = (const float*)d_in[23];
  const float* p3o = (const float*)d_in[24];

  char* w = (char*)d_ws;
  size_t off = 0;
  auto alloc = [&](size_t bytes) -> void* {
    void* p = w + off;
    off = (off + bytes + 255) & ~(size_t)255;
    return p;
  };
  float* BUF0 = (float*)alloc(32768ull * 512 * 4);
  float* BUF1 = (float*)alloc(19664ull * 512 * 4);
  short* XH = (short*)alloc(32768ull * 384 * 2);
  short* XM = (short*)alloc(32768ull * 384 * 2);
  short* XL = (short*)alloc(32768ull * 384 * 2);
  short* WTH = (short*)alloc(638976ull * 2);
  short* WTM = (short*)alloc(638976ull * 2);
  short* WTL = (short*)alloc(638976ull * 2);
  int* czone = (int*)alloc(65537ull * 4);
  int* cnt = czone;
  int* tmpc = czone + 32769;
  int* offs = (int*)alloc(32769 * 4);
  float* dis = (float*)alloc(32768 * 4);
  double* tvec = (double*)alloc(32768 * 8);
  double* rvec = (double*)alloc(32768 * 8);
  int* inv = (int*)alloc(32768 * 4);
  int* perm = (int*)alloc(32768 * 4);
  float* tanhv = (float*)alloc(32768 * 4);
  int* e0s = (int*)alloc(E_TOTAL * 4);
  int* e0d = (int*)alloc(E_TOTAL * 4);
  int* e1s = (int*)alloc(E_TOTAL * 4);
  int* e1d = (int*)alloc(E_TOTAL * 4);
  int* esrc = (int*)alloc(E_TOTAL * 4);
  double* bnsum = (double*)alloc((size_t)BNY * 512 * 8);
  double* bnsq = (double*)alloc((size_t)BNY * 512 * 8);
  float* bnscf = (float*)alloc(512 * 4);
  float* bnshf = (float*)alloc(512 * 4);
  double* bnscd = (double*)alloc(512 * 8);
  double* bnshd = (double*)alloc(512 * 8);
  float* part = (float*)alloc((size_t)NB * PCH * 2 * 192 * 4);

  const int EB = cdiv(E_TOTAL, 256);

  auto build_csr = [&](const int* src, const int* dst, int n) {
    scan_kernel<<<1, 1024, 0, stream>>>(cnt, offs, dis, n);
    scatter_kernel<<<EB, 256, 0, stream>>>(src, dst, offs, tmpc, esrc, E_TOTAL);
    sort_buckets<<<cdiv(n, 256), 256, 0, stream>>>(offs, esrc, n);
  };

  auto pool = [&](float* hbuf, int n, int n_pg, int k, int F,
                  const float* g, const float* be, const float* wr, const float* wb,
                  const float* wo, const int* src, const int* dst, int* nsrc, int* ndst) {
    bn_stats_part<<<dim3(cdiv(F, 256), BNY), 256, 0, stream>>>(hbuf, bnsum, bnsq, n, F);
    bn_reduce<<<F, 64, 0, stream>>>(bnsum, bnsq, g, be, bnscf, bnshf, bnscd, bnshd, n, F);
    score_dots<<<cdiv(n, 4), 256, 0, stream>>>(hbuf, bnscd, bnshd, wr, wo, tvec, rvec, F, n);
    topk_select<<<NB, 1024, 0, stream>>>(offs, esrc, tvec, rvec, wb, n_pg, k, perm, tanhv, inv);
    gather_split<<<cdiv(NB * k, 4), 256, 0, stream>>>(hbuf, perm, tanhv, bnscf, bnshf, XH, XM, XL, F, NB * k);
    fill_i32<<<cdiv(65537, 256), 256, 0, stream>>>(czone, 0, 65537);
    remap_kernel<<<EB, 256, 0, stream>>>(src, dst, inv, nsrc, ndst, cnt, E_TOTAL);
  };

  // weight split+transpose (3x bf16)
  split_w_t<<<cdiv(384 * 512, 256), 256, 0, stream>>>(W1, WTH, WTM, WTL, 384, 512);
  split_w_t<<<cdiv(512 * 512, 256), 256, 0, stream>>>(W2, WTH + 196608, WTM + 196608, WTL + 196608, 512, 512);
  split_w_t<<<cdiv(512 * 256, 256), 256, 0, stream>>>(W3, WTH + 458752, WTM + 458752, WTL + 458752, 512, 256);
  split_w_t<<<cdiv(256 * 192, 256), 256, 0, stream>>>(W4, WTH + 589824, WTM + 589824, WTL + 589824, 256, 192);

  // ---- Layer 1
  fill_i32<<<cdiv(65537, 256), 256, 0, stream>>>(czone, 0, 65537);
  count_kernel<<<EB, 256, 0, stream>>>(eidx + E_TOTAL, cnt, E_TOTAL);
  build_csr(eidx, eidx + E_TOTAL, 32768);
  agg_kernel<<<cdiv(32768, 4), 256, 0, stream>>>(x0, offs, esrc, dis, nullptr, nullptr, XH, XM, XL, 384, 32768);
  gemm_mfma<<<cdiv(32768, 128) * 2, 512, 0, stream>>>(XH, XM, XL, WTH, WTM, WTL, b1, BUF0, 32768, 384, 512, 2);
  pool(BUF0, 32768, 4096, 2458, 512, g1, be1, p1r, p1b, p1o, eidx, eidx + E_TOTAL, e0s, e0d);

  // ---- Layer 2
  build_csr(e0s, e0d, 19664);
  gemm_mfma<<<cdiv(19664, 128) * 2, 512, 0, stream>>>(XH, XM, XL, WTH + 196608, WTM + 196608, WTL + 196608, nullptr, BUF0, 19664, 512, 512, 2);
  agg_kernel<<<cdiv(19664, 4), 256, 0, stream>>>(BUF0, offs, esrc, dis, b2, BUF1, nullptr, nullptr, nullptr, 512, 19664);
  pool(BUF1, 19664, 2458, 1475, 512, g2, be2, p2r, p2b, p2o, e0s, e0d, e1s, e1d);

  // ---- Layer 3
  build_csr(e1s, e1d, 11800);
  gemm_mfma<<<cdiv(11800, 128), 512, 0, stream>>>(XH, XM, XL, WTH + 458752, WTM + 458752, WTL + 458752, nullptr, BUF0, 11800, 512, 256, 1);
  agg_kernel<<<cdiv(11800, 4), 256, 0, stream>>>(BUF0, offs, esrc, dis, b3, BUF1, nullptr, nullptr, nullptr, 256, 11800);
  pool(BUF1, 11800, 1475, 738, 256, g3, be3, p3r, p3b, p3o, e1s, e1d, e0s, e0d);

  // ---- Layer 4
  build_csr(e0s, e0d, 5904);
  gemm_mfma<<<cdiv(5904, 128), 512, 0, stream>>>(XH, XM, XL, WTH + 589824, WTM + 589824, WTL + 589824, nullptr, BUF0, 5904, 256, 192, 1);
  agg_kernel<<<cdiv(5904, 4), 256, 0, stream>>>(BUF0, offs, esrc, dis, b4, BUF1, nullptr, nullptr, nullptr, 192, 5904);
  pool_partial<<<dim3(NB, PCH), 192, 0, stream>>>(BUF1, part, 738, 192);
  pool_final<<<NB, 192, 0, stream>>>(part, (float*)d_out, 738, 192);
}

// Round 20
// 956.865 us; speedup vs baseline: 1.0769x; 1.0529x over previous
//
#include <hip/hip_runtime.h>
#include <cmath>

#define E_TOTAL 524288
#define NB 8

using f32x4 = __attribute__((ext_vector_type(4))) float;
using s16x8 = __attribute__((ext_vector_type(8))) short;
using s16x4 = __attribute__((ext_vector_type(4))) short;

static inline int cdiv(int a, int b) { return (a + b - 1) / b; }

__device__ inline unsigned short bf16_rn(float x) {
  unsigned u = __float_as_uint(x);
  return (unsigned short)((u + 0x7FFFu + ((u >> 16) & 1u)) >> 16);
}
// 3-chunk split: x ~= h + m + l with residual ~2^-24 |x|
__device__ inline void split3(float x, short& h, short& m, short& l) {
  unsigned short hb = bf16_rn(x);
  h = (short)hb;
  float hf = __uint_as_float(((unsigned)hb) << 16);
  float r1 = x - hf;
  unsigned short mb = bf16_rn(r1);
  m = (short)mb;
  float mf = __uint_as_float(((unsigned)mb) << 16);
  l = (short)bf16_rn(r1 - mf);
}

// async global->LDS 16B copy. LDS dest must be WAVE-UNIFORM; HW adds lane*16.
__device__ inline void async_copy16(const short* g, short* l) {
  __builtin_amdgcn_global_load_lds(
      (const __attribute__((address_space(1))) void*)(unsigned long long)(g),
      (__attribute__((address_space(3))) void*)(unsigned)(unsigned long long)(l),
      16, 0, 0);
}

// ---------------- fills ----------------
__global__ void fill_i32(int* p, int v, int n) {
  int i = blockIdx.x * 256 + threadIdx.x;
  if (i < n) p[i] = v;
}

// ---------------- weight split + transpose: W[K][N] fp32 -> WT[N][K] 3x bf16 ----------------
__global__ void split_w_t(const float* __restrict__ W, short* __restrict__ TH,
                          short* __restrict__ TM, short* __restrict__ TL, int K, int N) {
  int i = blockIdx.x * 256 + threadIdx.x;
  if (i >= K * N) return;
  int k = i / N, n = i % N;
  short h, m, l;
  split3(W[i], h, m, l);
  TH[(size_t)n * K + k] = h;
  TM[(size_t)n * K + k] = m;
  TL[(size_t)n * K + k] = l;
}

// ---------------- 3-chunk split-bf16 MFMA GEMM, double-buffered async LDS ----------------
#define GBM 128
#define GBN 256
#define GBK 32
#define BUFS 36864
#define BOFF 12288

__global__ __launch_bounds__(512) void gemm_mfma(
    const short* __restrict__ AH, const short* __restrict__ AM, const short* __restrict__ AL,
    const short* __restrict__ BH, const short* __restrict__ BM, const short* __restrict__ BL,
    const float* __restrict__ bias, float* __restrict__ C,
    int M, int K, int N, int nblocks) {
  __shared__ __align__(16) short lds[2][BUFS];
  int nwg = gridDim.x;
  int orig = blockIdx.x;
  int q = nwg >> 3, r = nwg & 7;
  int xc = orig & 7, j8 = orig >> 3;
  int wg = (xc < r ? xc * (q + 1) : r * (q + 1) + (xc - r) * q) + j8;
  int bm = (wg / nblocks) * GBM;
  int bn = (wg % nblocks) * GBN;
  int tid = threadIdx.x;
  int wave = tid >> 6, lane = tid & 63;
  int wr = wave >> 2, wc = wave & 3;
  int l15 = lane & 15, l4 = lane >> 4;
  int pa = wave * 64 + lane;
  int ra = pa >> 2, ca = (pa & 3) ^ ((ra >> 1) & 3);
  int gar = bm + ra; gar = gar < M ? gar : 0;
  size_t gaoff = (size_t)gar * K + ca * 8;
  int adest = wave * 512;
  int pb0 = wave * 128 + lane, pb1 = pb0 + 64;
  int rb0 = pb0 >> 2, cb0 = (pb0 & 3) ^ ((rb0 >> 1) & 3);
  int rb1 = pb1 >> 2, cb1 = (pb1 & 3) ^ ((rb1 >> 1) & 3);
  int gbr0 = bn + rb0; gbr0 = gbr0 < N ? gbr0 : 0;
  int gbr1 = bn + rb1; gbr1 = gbr1 < N ? gbr1 : 0;
  size_t gboff0 = (size_t)gbr0 * K + cb0 * 8;
  size_t gboff1 = (size_t)gbr1 * K + cb1 * 8;
  int bdest = BOFF + wave * 1024;

  auto stage = [&](int b, int k0) {
    short* base = lds[b];
    async_copy16(AH + gaoff + k0, base + adest);
    async_copy16(AM + gaoff + k0, base + 4096 + adest);
    async_copy16(AL + gaoff + k0, base + 8192 + adest);
    async_copy16(BH + gboff0 + k0, base + bdest);
    async_copy16(BH + gboff1 + k0, base + bdest + 512);
    async_copy16(BM + gboff0 + k0, base + 8192 + bdest);
    async_copy16(BM + gboff1 + k0, base + 8192 + bdest + 512);
    async_copy16(BL + gboff0 + k0, base + 16384 + bdest);
    async_copy16(BL + gboff1 + k0, base + 16384 + bdest + 512);
  };

  f32x4 acc[4][4] = {};
  int cur = 0;
  stage(0, 0);
  __syncthreads();
  for (int k0 = 0; k0 < K; k0 += GBK) {
    if (k0 + GBK < K) stage(cur ^ 1, k0 + GBK);
    const short* base = lds[cur];
    s16x8 fah[4], fam[4], fal[4], fbh[4], fbm[4], fbl[4];
#pragma unroll
    for (int mi = 0; mi < 4; ++mi) {
      int row = wr * 64 + mi * 16 + l15;
      int ad = row * 32 + ((l4 ^ ((row >> 1) & 3)) << 3);
      fah[mi] = *(const s16x8*)(base + ad);
      fam[mi] = *(const s16x8*)(base + 4096 + ad);
      fal[mi] = *(const s16x8*)(base + 8192 + ad);
    }
#pragma unroll
    for (int ni = 0; ni < 4; ++ni) {
      int row = wc * 64 + ni * 16 + l15;
      int bd = BOFF + row * 32 + ((l4 ^ ((row >> 1) & 3)) << 3);
      fbh[ni] = *(const s16x8*)(base + bd);
      fbm[ni] = *(const s16x8*)(base + 8192 + bd);
      fbl[ni] = *(const s16x8*)(base + 16384 + bd);
    }
#pragma unroll
    for (int mi = 0; mi < 4; ++mi)
#pragma unroll
      for (int ni = 0; ni < 4; ++ni) {
        acc[mi][ni] = __builtin_amdgcn_mfma_f32_16x16x32_bf16(fah[mi], fbh[ni], acc[mi][ni], 0, 0, 0);
        acc[mi][ni] = __builtin_amdgcn_mfma_f32_16x16x32_bf16(fah[mi], fbm[ni], acc[mi][ni], 0, 0, 0);
        acc[mi][ni] = __builtin_amdgcn_mfma_f32_16x16x32_bf16(fam[mi], fbh[ni], acc[mi][ni], 0, 0, 0);
        acc[mi][ni] = __builtin_amdgcn_mfma_f32_16x16x32_bf16(fah[mi], fbl[ni], acc[mi][ni], 0, 0, 0);
        acc[mi][ni] = __builtin_amdgcn_mfma_f32_16x16x32_bf16(fal[mi], fbh[ni], acc[mi][ni], 0, 0, 0);
        acc[mi][ni] = __builtin_amdgcn_mfma_f32_16x16x32_bf16(fam[mi], fbm[ni], acc[mi][ni], 0, 0, 0);
      }
    __syncthreads();
    cur ^= 1;
  }
#pragma unroll
  for (int ni = 0; ni < 4; ++ni) {
    int col = bn + wc * 64 + ni * 16 + l15;
    if (col >= N) continue;
    float bv = bias ? bias[col] : 0.f;
#pragma unroll
    for (int mi = 0; mi < 4; ++mi) {
      int row0 = bm + wr * 64 + mi * 16 + l4 * 4;
#pragma unroll
      for (int rr = 0; rr < 4; ++rr) {
        int row = row0 + rr;
        if (row < M) C[(size_t)row * N + col] = acc[mi][ni][rr] + bv;
      }
    }
  }
}

// ---------------- CSR build ----------------
__global__ void count_kernel(const int* __restrict__ dst, int* __restrict__ cnt, int E) {
  int e = blockIdx.x * 256 + threadIdx.x;
  if (e >= E) return;
  atomicAdd(&cnt[dst[e]], 1);
}

// scan + fused dis computation
__global__ __launch_bounds__(1024) void scan_kernel(const int* __restrict__ cnt,
                                                    int* __restrict__ offs,
                                                    float* __restrict__ dis, int n) {
  __shared__ int tsum[1024];
  int tid = threadIdx.x;
  int chunk = (n + 1023) / 1024;
  int base = tid * chunk;
  int lsum = 0;
  for (int i = 0; i < chunk; ++i) {
    int idx = base + i;
    if (idx < n) lsum += cnt[idx];
  }
  tsum[tid] = lsum;
  __syncthreads();
  for (int off = 1; off < 1024; off <<= 1) {
    int add = (tid >= off) ? tsum[tid - off] : 0;
    __syncthreads();
    tsum[tid] += add;
    __syncthreads();
  }
  int run = (tid == 0) ? 0 : tsum[tid - 1];
  for (int i = 0; i < chunk; ++i) {
    int idx = base + i;
    if (idx < n) {
      offs[idx] = run;
      int c = cnt[idx];
      run += c;
      dis[idx] = (c > 0) ? (float)(1.0 / sqrt((double)c)) : 0.f;
    }
  }
  if (tid == 1023) offs[n] = run;
}

__global__ void scatter_kernel(const int* __restrict__ src, const int* __restrict__ dst,
                               const int* __restrict__ offs, int* __restrict__ tmpc,
                               int* __restrict__ esrc, int E) {
  int e = blockIdx.x * 256 + threadIdx.x;
  if (e >= E) return;
  int d = dst[e];
  if (d < 0) return;
  int pos = offs[d] + atomicAdd(&tmpc[d], 1);
  esrc[pos] = src[e];
}

// canonicalize bucket order (determinism)
__global__ void sort_buckets(const int* __restrict__ offs, int* __restrict__ esrc, int n) {
  int node = blockIdx.x * 256 + threadIdx.x;
  if (node >= n) return;
  int s0 = offs[node], s1 = offs[node + 1];
  for (int i = s0 + 1; i < s1; ++i) {
    int v = esrc[i];
    int j = i - 1;
    while (j >= s0 && esrc[j] > v) { esrc[j + 1] = esrc[j]; --j; }
    esrc[j + 1] = v;
  }
}

// ---------------- aggregation (wave per node, f32x4, 4-way edge unroll) ----------------
__global__ __launch_bounds__(256) void agg_kernel(
    const float* __restrict__ h, const int* __restrict__ offs,
    const int* __restrict__ esrc, const float* __restrict__ dis,
    const float* __restrict__ bias, float* __restrict__ outf,
    short* __restrict__ outh, short* __restrict__ outm, short* __restrict__ outl,
    int F, int n) {
  int node = blockIdx.x * 4 + (threadIdx.x >> 6);
  if (node >= n) return;
  int lane = threadIdx.x & 63;
  int nf4 = F >> 2;
  int i0 = lane, i1 = lane + 64;
  bool a0 = i0 < nf4, a1 = i1 < nf4;
  f32x4 acc0 = {}, acc1 = {};
  int e0 = offs[node], e1 = offs[node + 1];
  int e = e0;
  for (; e + 4 <= e1; e += 4) {
    int s0 = esrc[e], s1 = esrc[e + 1], s2 = esrc[e + 2], s3 = esrc[e + 3];
    float w0 = dis[s0], w1 = dis[s1], w2 = dis[s2], w3 = dis[s3];
    const f32x4* p0 = (const f32x4*)(h + (size_t)s0 * F);
    const f32x4* p1 = (const f32x4*)(h + (size_t)s1 * F);
    const f32x4* p2 = (const f32x4*)(h + (size_t)s2 * F);
    const f32x4* p3 = (const f32x4*)(h + (size_t)s3 * F);
    if (a0) {
      f32x4 v0 = p0[i0], v1 = p1[i0], v2 = p2[i0], v3 = p3[i0];
      acc0 += v0 * w0;
      acc0 += v1 * w1;
      acc0 += v2 * w2;
      acc0 += v3 * w3;
    }
    if (a1) {
      f32x4 v0 = p0[i1], v1 = p1[i1], v2 = p2[i1], v3 = p3[i1];
      acc1 += v0 * w0;
      acc1 += v1 * w1;
      acc1 += v2 * w2;
      acc1 += v3 * w3;
    }
  }
  for (; e < e1; ++e) {
    int s = esrc[e];
    float w = dis[s];
    const f32x4* hp = (const f32x4*)(h + (size_t)s * F);
    if (a0) acc0 += hp[i0] * w;
    if (a1) acc1 += hp[i1] * w;
  }
  float wd = dis[node];
  acc0 *= wd;
  acc1 *= wd;
  if (outf) {
    const f32x4* b4 = (const f32x4*)bias;
    f32x4* op = (f32x4*)(outf + (size_t)node * F);
    if (a0) op[i0] = acc0 + b4[i0];
    if (a1) op[i1] = acc1 + b4[i1];
  } else {
    short hh[4], mm[4], ll[4];
    if (a0) {
#pragma unroll
      for (int c = 0; c < 4; ++c) split3(acc0[c], hh[c], mm[c], ll[c]);
      *(s16x4*)&outh[(size_t)node * F + i0 * 4] = *(s16x4*)hh;
      *(s16x4*)&outm[(size_t)node * F + i0 * 4] = *(s16x4*)mm;
      *(s16x4*)&outl[(size_t)node * F + i0 * 4] = *(s16x4*)ll;
    }
    if (a1) {
#pragma unroll
      for (int c = 0; c < 4; ++c) split3(acc1[c], hh[c], mm[c], ll[c]);
      *(s16x4*)&outh[(size_t)node * F + i1 * 4] = *(s16x4*)hh;
      *(s16x4*)&outm[(size_t)node * F + i1 * 4] = *(s16x4*)mm;
      *(s16x4*)&outl[(size_t)node * F + i1 * 4] = *(s16x4*)ll;
    }
  }
}

// ---------------- batch norm (two-stage fp64, atomic-free, deterministic) ----------------
#define BNY 512
__global__ void bn_stats_part(const float* __restrict__ x, double* __restrict__ psum,
                              double* __restrict__ psq, int n, int F) {
  int col = blockIdx.x * 256 + threadIdx.x;
  if (col >= F) return;
  double s = 0., q = 0.;
  for (int r = blockIdx.y; r < n; r += gridDim.y) {
    double v = (double)x[(size_t)r * F + col];
    s += v;
    q += v * v;
  }
  psum[blockIdx.y * F + col] = s;
  psq[blockIdx.y * F + col] = q;
}

// one block per column, 64-thread tree reduce (fixed order => deterministic)
__global__ __launch_bounds__(64) void bn_reduce(
    const double* __restrict__ psum, const double* __restrict__ psq,
    const float* __restrict__ g, const float* __restrict__ be,
    float* __restrict__ scf, float* __restrict__ shf,
    double* __restrict__ scd, double* __restrict__ shd, int n, int F) {
  int c = blockIdx.x;
  int lane = threadIdx.x;
  double s = 0., q = 0.;
  for (int p = lane; p < BNY; p += 64) {
    s += psum[p * F + c];
    q += psq[p * F + c];
  }
#pragma unroll
  for (int o = 1; o < 64; o <<= 1) {
    s += __shfl_xor(s, o, 64);
    q += __shfl_xor(q, o, 64);
  }
  if (lane == 0) {
    double inv_n = 1.0 / (double)n;
    double mu = s * inv_n;
    double var = q * inv_n - mu * mu;
    if (var < 0.) var = 0.;
    double istd = 1.0 / sqrt(var + 1e-5);
    double sc = istd * (double)g[c];
    double sh = (double)be[c] - mu * sc;
    scd[c] = sc;
    shd[c] = sh;
    scf[c] = (float)sc;
    shf[c] = (float)sh;
  }
}

// fp64 per-row dots with wrel/wroot (READ-ONLY)
__global__ __launch_bounds__(256) void score_dots(
    const float* __restrict__ hx,
    const double* __restrict__ scd, const double* __restrict__ shd,
    const float* __restrict__ wrel, const float* __restrict__ wroot,
    double* __restrict__ t, double* __restrict__ r, int F, int n) {
  int row = blockIdx.x * 4 + (threadIdx.x >> 6);
  if (row >= n) return;
  int lane = threadIdx.x & 63;
  int nf4 = F >> 2;
  const f32x4* hp = (const f32x4*)(hx + (size_t)row * F);
  double dr = 0., dq = 0.;
  for (int j = lane; j < nf4; j += 64) {
    f32x4 hv = hp[j];
#pragma unroll
    for (int c = 0; c < 4; ++c) {
      double vd = (double)hv[c] * scd[j * 4 + c] + shd[j * 4 + c];
      vd = vd > 0. ? vd : 0.;
      dr += vd * (double)wrel[j * 4 + c];
      dq += vd * (double)wroot[j * 4 + c];
    }
  }
#pragma unroll
  for (int o = 1; o < 64; o <<= 1) {
    dr += __shfl_xor(dr, o, 64);
    dq += __shfl_xor(dq, o, 64);
  }
  if (lane == 0) { t[row] = dr; r[row] = dq; }
}

// s[i] = sum_{e into i} t[src] + r[i] + brel   (fp64, sorted order, deterministic)
__global__ void score_kernel(const int* __restrict__ offs, const int* __restrict__ esrc,
                             const double* __restrict__ t, const double* __restrict__ r,
                             const float* __restrict__ brel, double* __restrict__ s, int n) {
  int i = blockIdx.x * 256 + threadIdx.x;
  if (i >= n) return;
  double acc = 0.;
  int e0 = offs[i], e1 = offs[i + 1];
  for (int e = e0; e < e1; ++e) acc += t[esrc[e]];
  s[i] = acc + r[i] + (double)brel[0];
}

// ---------------- per-graph top-k via radix-select + index-order compaction ----------------
__global__ __launch_bounds__(1024) void topk_select(
    const double* __restrict__ s, int n_pg, int k,
    int* __restrict__ perm, float* __restrict__ tanhv, int* __restrict__ inv) {
  __shared__ unsigned hist[256];
  __shared__ unsigned long long sPfx;
  __shared__ int sRem;
  __shared__ unsigned wsum[16];
  __shared__ unsigned woff[4];
  int g = blockIdx.x;
  int tid = threadIdx.x;
  const double* sg = s + (size_t)g * n_pg;
  auto keyof = [&](int i) -> unsigned long long {
    unsigned long long u = (unsigned long long)__double_as_longlong(sg[i]);
    u = (u >> 63) ? ~u : (u | 0x8000000000000000ULL);
    return ((u >> 12) << 12) | (unsigned long long)(4095 - i);
  };
  unsigned long long prefix = 0;
  int rem = k;
  for (int shift = 56; shift >= 0; shift -= 8) {
    if (tid < 256) hist[tid] = 0;
    __syncthreads();
    unsigned long long himask = (shift == 56) ? 0ULL : (~0ULL << (shift + 8));
    for (int i = tid; i < n_pg; i += 1024) {
      unsigned long long kk = keyof(i);
      if ((kk & himask) == prefix) {
        unsigned b = (unsigned)((kk >> shift) & 255);
        atomicAdd(&hist[b], 1u);
      }
    }
    __syncthreads();
    unsigned a = 0, v = 0;
    int slane = 0, swid = 0;
    if (tid < 256) {
      int rrev = 255 - tid;
      a = hist[tid];
      v = a;
      slane = rrev & 63;
      swid = rrev >> 6;
      for (int o = 1; o < 64; o <<= 1) {
        unsigned u2 = __shfl_down(v, o, 64);
        if (slane >= o) v += u2;
      }
      if (slane == 63) woff[swid] = v;
    }
    __syncthreads();
    if (tid < 256) {
      unsigned base2 = 0;
      for (int wi = 0; wi < swid; ++wi) base2 += woff[wi];
      unsigned Sinc = base2 + v;
      unsigned Sexc = Sinc - a;
      if ((int)Sexc < rem && (int)Sinc >= rem) {
        sPfx = prefix | (((unsigned long long)tid) << shift);
        sRem = rem - (int)Sexc;
      }
    }
    __syncthreads();
    prefix = sPfx;
    rem = sRem;
    __syncthreads();
  }
  unsigned long long Kstar = prefix;
  int c = (n_pg + 1023) / 1024;
  int base = tid * c;
  int loc[4];
  int cnt = 0;
#pragma unroll 4
  for (int j = 0; j < c; ++j) {
    int i = base + j;
    int sel = (i < n_pg && keyof(i) >= Kstar) ? 1 : 0;
    loc[j] = cnt;
    cnt += sel;
  }
  int lane = tid & 63, wid = tid >> 6;
  int v2 = cnt;
  for (int o = 1; o < 64; o <<= 1) {
    int u2 = __shfl_up(v2, o, 64);
    if (lane >= o) v2 += u2;
  }
  int wexcl = v2 - cnt;
  if (lane == 63) wsum[wid] = (unsigned)v2;
  __syncthreads();
  if (tid == 0) {
    unsigned run = 0;
    for (int wi = 0; wi < 16; ++wi) { unsigned t2 = wsum[wi]; wsum[wi] = run; run += t2; }
  }
  __syncthreads();
  int offset = (int)wsum[wid] + wexcl;
  for (int j = 0; j < c; ++j) {
    int i = base + j;
    if (i >= n_pg) break;
    bool sel = keyof(i) >= Kstar;
    int old_g = g * n_pg + i;
    if (sel) {
      int new_g = g * k + offset + loc[j];
      perm[new_g] = old_g;
      tanhv[new_g] = (float)tanh(sg[i]);
      inv[old_g] = new_g;
    } else {
      inv[old_g] = -1;
    }
  }
}

// gather kept rows; apply BN scale/shift + relu + tanh, emit 3-chunk bf16
__global__ __launch_bounds__(256) void gather_split(
    const float* __restrict__ h, const int* __restrict__ perm,
    const float* __restrict__ tanhv,
    const float* __restrict__ scf, const float* __restrict__ shf,
    short* __restrict__ gh, short* __restrict__ gm,
    short* __restrict__ gl, int F, int nk) {
  int i = blockIdx.x * 4 + (threadIdx.x >> 6);
  if (i >= nk) return;
  int lane = threadIdx.x & 63;
  int nf4 = F >> 2;
  int p = perm[i];
  float tv = tanhv[i];
  const f32x4* hp = (const f32x4*)(h + (size_t)p * F);
  const f32x4* sc = (const f32x4*)scf;
  const f32x4* sh = (const f32x4*)shf;
  for (int j = lane; j < nf4; j += 64) {
    f32x4 v = hp[j] * sc[j] + sh[j];
#pragma unroll
    for (int c = 0; c < 4; ++c) v[c] = fmaxf(v[c], 0.f);
    v *= tv;
    short hh[4], mm[4], ll[4];
#pragma unroll
    for (int c = 0; c < 4; ++c) split3(v[c], hh[c], mm[c], ll[c]);
    *(s16x4*)&gh[(size_t)i * F + j * 4] = *(s16x4*)hh;
    *(s16x4*)&gm[(size_t)i * F + j * 4] = *(s16x4*)mm;
    *(s16x4*)&gl[(size_t)i * F + j * 4] = *(s16x4*)ll;
  }
}

// remap edges to new ids + count next-layer in-degrees (int atomics: deterministic)
__global__ void remap_kernel(const int* __restrict__ src_in, const int* __restrict__ dst_in,
                             const int* __restrict__ inv, int* __restrict__ src_out,
                             int* __restrict__ dst_out, int* __restrict__ cnt, int E) {
  int e = blockIdx.x * 256 + threadIdx.x;
  if (e >= E) return;
  int d = dst_in[e];
  int ns = -1, nd = -1;
  if (d >= 0) { ns = inv[src_in[e]]; nd = inv[d]; }
  if (ns >= 0 && nd >= 0) {
    src_out[e] = ns;
    dst_out[e] = nd;
    atomicAdd(&cnt[nd], 1);
  } else {
    src_out[e] = 0;
    dst_out[e] = -1;
  }
}

// ---------------- final global mean+max pool (two stage) ----------------
#define PCH 16
__global__ void pool_partial(const float* __restrict__ h, float* __restrict__ part,
                             int k3, int F) {
  int g = blockIdx.x, c = blockIdx.y;
  int tid = threadIdx.x;
  int chunk = (k3 + PCH - 1) / PCH;
  int r0 = c * chunk, r1 = min(r0 + chunk, k3);
  const float* base = h + (size_t)g * k3 * F;
  float sm = 0.f, mx = -INFINITY;
  for (int r = r0; r < r1; ++r) {
    float v = base[(size_t)r * F + tid];
    sm += v;
    mx = fmaxf(mx, v);
  }
  float* pp = part + (size_t)(g * PCH + c) * 2 * F;
  pp[tid] = sm;
  pp[F + tid] = mx;
}
__global__ void pool_final(const float* __restrict__ part, float* __restrict__ out,
                           int k3, int F) {
  int g = blockIdx.x;
  int tid = threadIdx.x;
  float sm = 0.f, mx = -INFINITY;
  for (int c = 0; c < PCH; ++c) {
    const float* pp = part + (size_t)(g * PCH + c) * 2 * F;
    sm += pp[tid];
    mx = fmaxf(mx, pp[F + tid]);
  }
  out[g * F + tid] = sm / (float)k3 + mx;
}

extern "C" void kernel_launch(void* const* d_in, const int* in_sizes, int n_in,
                              void* d_out, int out_size, void* d_ws, size_t ws_size,
                              hipStream_t stream) {
  const float* x0 = (const float*)d_in[0];
  const int* eidx = (const int*)d_in[1];
  const float* W1 = (const float*)d_in[2];  const float* b1 = (const float*)d_in[3];
  const float* W2 = (const float*)d_in[4];  const float* b2 = (const float*)d_in[5];
  const float* W3 = (const float*)d_in[6];  const float* b3 = (const float*)d_in[7];
  const float* W4 = (const float*)d_in[8];  const float* b4 = (const float*)d_in[9];
  const float* g1 = (const float*)d_in[10]; const float* be1 = (const float*)d_in[11];
  const float* g2 = (const float*)d_in[12]; const float* be2 = (const float*)d_in[13];
  const float* g3 = (const float*)d_in[14]; const float* be3 = (const float*)d_in[15];
  const float* p1r = (const float*)d_in[16]; const float* p1b = (const float*)d_in[17];
  const float* p1o = (const float*)d_in[18];
  const float* p2r = (const float*)d_in[19]; const float* p2b = (const float*)d_in[20];
  const float* p2o = (const float*)d_in[21];
  const float* p3r = (const float*)d_in[22]; const float* p3b = (const float*)d_in[23];
  const float* p3o = (const float*)d_in[24];

  char* w = (char*)d_ws;
  size_t off = 0;
  auto alloc = [&](size_t bytes) -> void* {
    void* p = w + off;
    off = (off + bytes + 255) & ~(size_t)255;
    return p;
  };
  float* BUF0 = (float*)alloc(32768ull * 512 * 4);
  float* BUF1 = (float*)alloc(19664ull * 512 * 4);
  short* XH = (short*)alloc(32768ull * 384 * 2);
  short* XM = (short*)alloc(32768ull * 384 * 2);
  short* XL = (short*)alloc(32768ull * 384 * 2);
  short* WTH = (short*)alloc(638976ull * 2);
  short* WTM = (short*)alloc(638976ull * 2);
  short* WTL = (short*)alloc(638976ull * 2);
  int* czone = (int*)alloc(65537ull * 4);
  int* cnt = czone;
  int* tmpc = czone + 32769;
  int* offs = (int*)alloc(32769 * 4);
  float* dis = (float*)alloc(32768 * 4);
  double* tvec = (double*)alloc(32768 * 8);
  double* rvec = (double*)alloc(32768 * 8);
  double* svec = (double*)alloc(32768 * 8);
  int* inv = (int*)alloc(32768 * 4);
  int* perm = (int*)alloc(32768 * 4);
  float* tanhv = (float*)alloc(32768 * 4);
  int* e0s = (int*)alloc(E_TOTAL * 4);
  int* e0d = (int*)alloc(E_TOTAL * 4);
  int* e1s = (int*)alloc(E_TOTAL * 4);
  int* e1d = (int*)alloc(E_TOTAL * 4);
  int* esrc = (int*)alloc(E_TOTAL * 4);
  double* bnsum = (double*)alloc((size_t)BNY * 512 * 8);
  double* bnsq = (double*)alloc((size_t)BNY * 512 * 8);
  float* bnscf = (float*)alloc(512 * 4);
  float* bnshf = (float*)alloc(512 * 4);
  double* bnscd = (double*)alloc(512 * 8);
  double* bnshd = (double*)alloc(512 * 8);
  float* part = (float*)alloc((size_t)NB * PCH * 2 * 192 * 4);

  const int EB = cdiv(E_TOTAL, 256);

  auto build_csr = [&](const int* src, const int* dst, int n) {
    scan_kernel<<<1, 1024, 0, stream>>>(cnt, offs, dis, n);
    scatter_kernel<<<EB, 256, 0, stream>>>(src, dst, offs, tmpc, esrc, E_TOTAL);
    sort_buckets<<<cdiv(n, 256), 256, 0, stream>>>(offs, esrc, n);
  };

  auto pool = [&](float* hbuf, int n, int n_pg, int k, int F,
                  const float* g, const float* be, const float* wr, const float* wb,
                  const float* wo, const int* src, const int* dst, int* nsrc, int* ndst) {
    bn_stats_part<<<dim3(cdiv(F, 256), BNY), 256, 0, stream>>>(hbuf, bnsum, bnsq, n, F);
    bn_reduce<<<F, 64, 0, stream>>>(bnsum, bnsq, g, be, bnscf, bnshf, bnscd, bnshd, n, F);
    score_dots<<<cdiv(n, 4), 256, 0, stream>>>(hbuf, bnscd, bnshd, wr, wo, tvec, rvec, F, n);
    score_kernel<<<cdiv(n, 256), 256, 0, stream>>>(offs, esrc, tvec, rvec, wb, svec, n);
    topk_select<<<NB, 1024, 0, stream>>>(svec, n_pg, k, perm, tanhv, inv);
    gather_split<<<cdiv(NB * k, 4), 256, 0, stream>>>(hbuf, perm, tanhv, bnscf, bnshf, XH, XM, XL, F, NB * k);
    fill_i32<<<cdiv(65537, 256), 256, 0, stream>>>(czone, 0, 65537);
    remap_kernel<<<EB, 256, 0, stream>>>(src, dst, inv, nsrc, ndst, cnt, E_TOTAL);
  };

  // weight split+transpose (3x bf16)
  split_w_t<<<cdiv(384 * 512, 256), 256, 0, stream>>>(W1, WTH, WTM, WTL, 384, 512);
  split_w_t<<<cdiv(512 * 512, 256), 256, 0, stream>>>(W2, WTH + 196608, WTM + 196608, WTL + 196608, 512, 512);
  split_w_t<<<cdiv(512 * 256, 256), 256, 0, stream>>>(W3, WTH + 458752, WTM + 458752, WTL + 458752, 512, 256);
  split_w_t<<<cdiv(256 * 192, 256), 256, 0, stream>>>(W4, WTH + 589824, WTM + 589824, WTL + 589824, 256, 192);

  // ---- Layer 1
  fill_i32<<<cdiv(65537, 256), 256, 0, stream>>>(czone, 0, 65537);
  count_kernel<<<EB, 256, 0, stream>>>(eidx + E_TOTAL, cnt, E_TOTAL);
  build_csr(eidx, eidx + E_TOTAL, 32768);
  agg_kernel<<<cdiv(32768, 4), 256, 0, stream>>>(x0, offs, esrc, dis, nullptr, nullptr, XH, XM, XL, 384, 32768);
  gemm_mfma<<<cdiv(32768, 128) * 2, 512, 0, stream>>>(XH, XM, XL, WTH, WTM, WTL, b1, BUF0, 32768, 384, 512, 2);
  pool(BUF0, 32768, 4096, 2458, 512, g1, be1, p1r, p1b, p1o, eidx, eidx + E_TOTAL, e0s, e0d);

  // ---- Layer 2
  build_csr(e0s, e0d, 19664);
  gemm_mfma<<<cdiv(19664, 128) * 2, 512, 0, stream>>>(XH, XM, XL, WTH + 196608, WTM + 196608, WTL + 196608, nullptr, BUF0, 19664, 512, 512, 2);
  agg_kernel<<<cdiv(19664, 4), 256, 0, stream>>>(BUF0, offs, esrc, dis, b2, BUF1, nullptr, nullptr, nullptr, 512, 19664);
  pool(BUF1, 19664, 2458, 1475, 512, g2, be2, p2r, p2b, p2o, e0s, e0d, e1s, e1d);

  // ---- Layer 3
  build_csr(e1s, e1d, 11800);
  gemm_mfma<<<cdiv(11800, 128), 512, 0, stream>>>(XH, XM, XL, WTH + 458752, WTM + 458752, WTL + 458752, nullptr, BUF0, 11800, 512, 256, 1);
  agg_kernel<<<cdiv(11800, 4), 256, 0, stream>>>(BUF0, offs, esrc, dis, b3, BUF1, nullptr, nullptr, nullptr, 256, 11800);
  pool(BUF1, 11800, 1475, 738, 256, g3, be3, p3r, p3b, p3o, e1s, e1d, e0s, e0d);

  // ---- Layer 4
  build_csr(e0s, e0d, 5904);
  gemm_mfma<<<cdiv(5904, 128), 512, 0, stream>>>(XH, XM, XL, WTH + 589824, WTM + 589824, WTL + 589824, nullptr, BUF0, 5904, 256, 192, 1);
  agg_kernel<<<cdiv(5904, 4), 256, 0, stream>>>(BUF0, offs, esrc, dis, b4, BUF1, nullptr, nullptr, nullptr, 192, 5904);
  pool_partial<<<dim3(NB, PCH), 192, 0, stream>>>(BUF1, part, 738, 192);
  pool_final<<<NB, 192, 0, stream>>>(part, (float*)d_out, 738, 192);
}